// Round 3
// baseline (6448.217 us; speedup 1.0000x reference)
//
#include <hip/hip_runtime.h>
#include <stdint.h>

// Problem dims
#define N_ 64
#define T_ 256
#define K_ 4

#define DL 300
#define HL 300
#define H4L 1200

#define DA 88
#define HA 64
#define H4A 256

#define DI 128
#define HI 128
#define H4I 512

__device__ __forceinline__ float sigf(float x) { return 1.0f / (1.0f + expf(-x)); }

// Mask dtype detected at runtime: 0 = int32, 1 = uint8, 2 = float32.
__device__ __forceinline__ int read_mask(const void* m, size_t idx, int mode) {
    if (mode == 0) return ((const int*)m)[idx];
    if (mode == 1) return (int)((const unsigned char*)m)[idx];
    return ((const float*)m)[idx] != 0.0f;
}

__global__ void mask_mode_detect(const unsigned int* __restrict__ m, int* __restrict__ modep) {
    __shared__ unsigned int f[2];
    if (threadIdx.x == 0) { f[0] = 0u; f[1] = 0u; }
    __syncthreads();
    unsigned int gt1 = 0, f32one = 0;
    for (int i = threadIdx.x; i < 4096; i += 256) {
        const unsigned int v = m[i];
        if (v > 1u) gt1 = 1u;
        if (v == 0x3F800000u) f32one = 1u;
    }
    if (gt1) atomicOr(&f[0], 1u);
    if (f32one) atomicOr(&f[1], 1u);
    __syncthreads();
    if (threadIdx.x == 0) modep[0] = f[0] ? (f[1] ? 2 : 1) : 0;
}

// ---------------------------------------------------------------------------
// xproj GEMM: XZ[r][j] = sum_d Xrow(r)[d] * W[j][d] + bih[j] + bhh[j]
// r = (n*Tc + tt)*4 + k within the current t-chunk; tile skipped if all rows
// have t >= seq_len[n].
// ---------------------------------------------------------------------------
__global__ __launch_bounds__(256) void gemm_xz(
    const float* __restrict__ X, const float* __restrict__ W,
    const float* __restrict__ bih, const float* __restrict__ bhh,
    const int* __restrict__ seqlen,
    float* __restrict__ XZ,
    int D, int H4, int Tc, int t0)
{
    __shared__ __align__(16) float As[16][68];
    __shared__ __align__(16) float Bs[16][68];
    const int tid = threadIdx.x;
    const int m0 = blockIdx.y * 64;
    const int j0 = blockIdx.x * 64;
    const int Tc4 = Tc * 4;

    int act = 0;
    if (tid < 64) {
        const int rr = m0 + tid;
        const int n = rr / Tc4;
        const int ttt = (rr % Tc4) >> 2;
        act = (t0 + ttt) < seqlen[n];
    }
    if (!__syncthreads_or(act)) return;

    const int lc = tid & 15;
    const int lr = tid >> 4;
    const float* arow[4];
#pragma unroll
    for (int i = 0; i < 4; ++i) {
        const int rr = m0 + lr + 16 * i;
        const int n = rr / Tc4;
        const int ttt = (rr % Tc4) >> 2;
        const int k = rr & 3;
        arow[i] = X + ((size_t)((n * T_ + t0 + ttt) * 4 + k)) * D;
    }
    const int ty = tid >> 4;
    const int tx = tid & 15;
    float acc[4][4] = {};
    const int nkt = (D + 15) >> 4;
    for (int kt = 0; kt < nkt; ++kt) {
        const int d = kt * 16 + lc;
#pragma unroll
        for (int i = 0; i < 4; ++i) {
            As[lc][lr + 16 * i] = (d < D) ? arow[i][d] : 0.0f;
            const int jr = j0 + lr + 16 * i;
            Bs[lc][lr + 16 * i] = (d < D && jr < H4) ? W[(size_t)jr * D + d] : 0.0f;
        }
        __syncthreads();
#pragma unroll
        for (int kk = 0; kk < 16; ++kk) {
            const float4 av = *(const float4*)&As[kk][ty * 4];
            const float4 bv = *(const float4*)&Bs[kk][tx * 4];
            acc[0][0] += av.x * bv.x; acc[0][1] += av.x * bv.y; acc[0][2] += av.x * bv.z; acc[0][3] += av.x * bv.w;
            acc[1][0] += av.y * bv.x; acc[1][1] += av.y * bv.y; acc[1][2] += av.y * bv.z; acc[1][3] += av.y * bv.w;
            acc[2][0] += av.z * bv.x; acc[2][1] += av.z * bv.y; acc[2][2] += av.z * bv.z; acc[2][3] += av.z * bv.w;
            acc[3][0] += av.w * bv.x; acc[3][1] += av.w * bv.y; acc[3][2] += av.w * bv.z; acc[3][3] += av.w * bv.w;
        }
        __syncthreads();
    }
    const int col = j0 + tx * 4;
    if (col < H4) {
        const float4 bi = *(const float4*)&bih[col];
        const float4 bh = *(const float4*)&bhh[col];
        const float bx = bi.x + bh.x, by = bi.y + bh.y, bz = bi.z + bh.z, bw = bi.w + bh.w;
#pragma unroll
        for (int i = 0; i < 4; ++i) {
            const int rr = m0 + ty * 4 + i;
            float4 v;
            v.x = acc[i][0] + bx; v.y = acc[i][1] + by; v.z = acc[i][2] + bz; v.w = acc[i][3] + bw;
            *(float4*)&XZ[(size_t)rr * H4 + col] = v;
        }
    }
}

// ---------------------------------------------------------------------------
// Image + acoustic recurrences. 128 blocks x 512 threads.
// ---------------------------------------------------------------------------
__global__ __launch_bounds__(512, 2) void recur_small(
    const float* __restrict__ WhhA, const float* __restrict__ WhhI,
    const void* __restrict__ mA, const void* __restrict__ mI,
    const int* __restrict__ modep,
    const int* __restrict__ seqlen,
    const float* __restrict__ xzA, const float* __restrict__ xzI,
    float* __restrict__ hsA, float* __restrict__ hsI,
    float* __restrict__ hcA, float* __restrict__ hcI,
    int Tc, int t0)
{
    __shared__ __align__(16) float h_s[128];
    __shared__ __align__(16) float c_s[128];
    __shared__ __align__(16) float z_s[512];
    const int tid = threadIdx.x;
    const int mode = modep[0];

    if (blockIdx.x < N_) {
        // ---------------- image ----------------
        const int n = blockIdx.x;
        const int seqn = seqlen[n];
        float w[128];
        {
            const float4* wp = (const float4*)(WhhI + (size_t)tid * 128);
#pragma unroll
            for (int jj = 0; jj < 32; ++jj) {
                const float4 v = wp[jj];
                w[4 * jj] = v.x; w[4 * jj + 1] = v.y; w[4 * jj + 2] = v.z; w[4 * jj + 3] = v.w;
            }
        }
        if (tid < 128) {
            if (t0 == 0) { h_s[tid] = 0.0f; c_s[tid] = 0.0f; }
            else { h_s[tid] = hcI[n * 256 + tid]; c_s[tid] = hcI[n * 256 + 128 + tid]; }
        }
        __syncthreads();
#pragma unroll 1
        for (int tt = 0; tt < Tc; ++tt) {
            const int t = t0 + tt;
            if (t >= seqn) {
                if (tid < 128) hsI[((size_t)(n * T_ + t)) * 128 + tid] = 0.0f;
                continue;
            }
            const size_t xbase = ((size_t)((n * Tc + tt) * 4)) * 512;
            const size_t mbase = (size_t)(n * T_ + t) * 4;
#pragma unroll 1
            for (int k = 0; k < 4; ++k) {
                if (!read_mask(mI, mbase + k, mode)) continue;
                float acc = xzI[xbase + k * 512 + tid];
                const float4* hp = (const float4*)h_s;
#pragma unroll
                for (int jj = 0; jj < 32; ++jj) {
                    const float4 hv = hp[jj];
                    acc += w[4 * jj] * hv.x + w[4 * jj + 1] * hv.y
                         + w[4 * jj + 2] * hv.z + w[4 * jj + 3] * hv.w;
                }
                z_s[tid] = acc;
                __syncthreads();
                if (tid < 128) {
                    const float zi = z_s[tid], zf = z_s[128 + tid];
                    const float zg = z_s[256 + tid], zo = z_s[384 + tid];
                    const float cc = sigf(zf) * c_s[tid] + sigf(zi) * tanhf(zg);
                    c_s[tid] = cc;
                    h_s[tid] = sigf(zo) * tanhf(cc);
                }
                __syncthreads();
            }
            if (tid < 128) hsI[((size_t)(n * T_ + t)) * 128 + tid] = h_s[tid];
        }
        if (tid < 128) { hcI[n * 256 + tid] = h_s[tid]; hcI[n * 256 + 128 + tid] = c_s[tid]; }
    } else {
        // ---------------- acoustic ----------------
        const int n = blockIdx.x - N_;
        const int seqn = seqlen[n];
        float w[64];
        if (tid < 256) {
            const float4* wp = (const float4*)(WhhA + (size_t)tid * 64);
#pragma unroll
            for (int jj = 0; jj < 16; ++jj) {
                const float4 v = wp[jj];
                w[4 * jj] = v.x; w[4 * jj + 1] = v.y; w[4 * jj + 2] = v.z; w[4 * jj + 3] = v.w;
            }
        }
        if (tid < 64) {
            if (t0 == 0) { h_s[tid] = 0.0f; c_s[tid] = 0.0f; }
            else { h_s[tid] = hcA[n * 128 + tid]; c_s[tid] = hcA[n * 128 + 64 + tid]; }
        }
        __syncthreads();
#pragma unroll 1
        for (int tt = 0; tt < Tc; ++tt) {
            const int t = t0 + tt;
            if (t >= seqn) {
                if (tid < 64) hsA[((size_t)(n * T_ + t)) * 64 + tid] = 0.0f;
                continue;
            }
            const size_t xbase = ((size_t)((n * Tc + tt) * 4)) * 256;
            const size_t mbase = (size_t)(n * T_ + t) * 4;
#pragma unroll 1
            for (int k = 0; k < 4; ++k) {
                if (!read_mask(mA, mbase + k, mode)) continue;
                if (tid < 256) {
                    float acc = xzA[xbase + k * 256 + tid];
                    const float4* hp = (const float4*)h_s;
#pragma unroll
                    for (int jj = 0; jj < 16; ++jj) {
                        const float4 hv = hp[jj];
                        acc += w[4 * jj] * hv.x + w[4 * jj + 1] * hv.y
                             + w[4 * jj + 2] * hv.z + w[4 * jj + 3] * hv.w;
                    }
                    z_s[tid] = acc;
                }
                __syncthreads();
                if (tid < 64) {
                    const float zi = z_s[tid], zf = z_s[64 + tid];
                    const float zg = z_s[128 + tid], zo = z_s[192 + tid];
                    const float cc = sigf(zf) * c_s[tid] + sigf(zi) * tanhf(zg);
                    c_s[tid] = cc;
                    h_s[tid] = sigf(zo) * tanhf(cc);
                }
                __syncthreads();
            }
            if (tid < 64) hsA[((size_t)(n * T_ + t)) * 64 + tid] = h_s[tid];
        }
        if (tid < 64) { hcA[n * 128 + tid] = h_s[tid]; hcA[n * 128 + 64 + tid] = c_s[tid]; }
    }
}

// ---------------------------------------------------------------------------
// Linguistic recurrence: 4 blocks per sample (one per gate), 256 threads,
// gate's 300x300 Whh slice register-resident (375 w-regs/thread, 1 blk/CU).
// Cross-block exchange: parity double-buffered zbuf[N][4][2][304] published
// with agent-scope atomic stores, consumed with agent-scope atomic loads
// (bypass stale L1); 4-block spin barrier on monotone counter cnt[n].
// 256 blocks at 1 block/CU: all co-resident, deadlock-free.
// ---------------------------------------------------------------------------
__global__ __launch_bounds__(256, 1) void recur_ling(
    const float* __restrict__ Whh,
    const void* __restrict__ mask,
    const int* __restrict__ modep,
    const int* __restrict__ seqlen,
    const float* __restrict__ xz,
    float* __restrict__ hs,
    float* __restrict__ hc,
    float* __restrict__ zbuf,       // [N][4][2][304]
    unsigned int* __restrict__ cnt, // [N], zeroed before each launch
    int Tc, int t0)
{
    __shared__ float h_s[304];
    __shared__ float c_s[304];
    __shared__ float zp_s[1200];
    const int tid = threadIdx.x;
    const int n = blockIdx.x >> 2;
    const int g = blockIdx.x & 3;
    const int seqn = seqlen[n];
    const int mode = modep[0];

    // chunk = tid&3 owns cols [chunk*75, +75); rows r = (tid>>2) + 64*s.
    const int chunk = tid & 3;
    const int rb = tid >> 2;
    float w[5][75];
#pragma unroll
    for (int s = 0; s < 5; ++s) {
        int r = rb + 64 * s;
        if (r >= 300) r = 299;  // dup load; store side is guarded
        const float* wp = Whh + ((size_t)(g * 300 + r)) * 300 + chunk * 75;
#pragma unroll
        for (int j = 0; j < 75; ++j) w[s][j] = wp[j];
    }
    for (int r = tid; r < 300; r += 256) {
        if (t0 == 0) { h_s[r] = 0.0f; c_s[r] = 0.0f; }
        else { h_s[r] = hc[n * 600 + r]; c_s[r] = hc[n * 600 + 300 + r]; }
    }
    __syncthreads();

    unsigned int serial = 0;  // completed exchange rounds (identical across the 4 blocks)
    unsigned int* const cntn = &cnt[n];
    float* const pub = zbuf + ((size_t)(n * 4 + g)) * 2 * 304;
    float* const zb  = zbuf + (size_t)n * 8 * 304;   // slot (g,par) at (g*2+par)*304

#pragma unroll 1
    for (int tt = 0; tt < Tc; ++tt) {
        const int t = t0 + tt;
        if (t >= seqn) {
            if (g == 0)
                for (int r = tid; r < 300; r += 256)
                    hs[((size_t)(n * T_ + t)) * 300 + r] = 0.0f;
            continue;
        }
        const size_t mbase = (size_t)(n * T_ + t) * 4;
        const float* xzt = xz + ((size_t)((n * Tc + tt) * 4)) * 1200;
#pragma unroll 1
        for (int k = 0; k < 4; ++k) {
            if (!read_mask(mask, mbase + k, mode)) continue;
            const int par = (int)(serial & 1u);
            float a0 = 0.f, a1 = 0.f, a2 = 0.f, a3 = 0.f, a4 = 0.f;
#pragma unroll
            for (int j = 0; j < 75; ++j) {
                const float hv = h_s[chunk * 75 + j];  // 4 addrs/wave: broadcast
                a0 += w[0][j] * hv;
                a1 += w[1][j] * hv;
                a2 += w[2][j] * hv;
                a3 += w[3][j] * hv;
                a4 += w[4][j] * hv;
            }
            zp_s[chunk * 300 + rb]       = a0;
            zp_s[chunk * 300 + rb + 64]  = a1;
            zp_s[chunk * 300 + rb + 128] = a2;
            zp_s[chunk * 300 + rb + 192] = a3;
            if (rb < 44) zp_s[chunk * 300 + rb + 256] = a4;
            __syncthreads();
            // reduce 4 col-chunks + xz slice; publish this gate's z (parity slot)
            const float* xg = xzt + k * 1200 + g * 300;
            for (int r = tid; r < 300; r += 256) {
                const float z = xg[r] + zp_s[r] + zp_s[300 + r] + zp_s[600 + r] + zp_s[900 + r];
                __hip_atomic_store(&pub[par * 304 + r], z, __ATOMIC_RELAXED, __HIP_MEMORY_SCOPE_AGENT);
            }
            __syncthreads();
            if (tid == 0) {
                __hip_atomic_fetch_add(cntn, 1u, __ATOMIC_RELEASE, __HIP_MEMORY_SCOPE_AGENT);
                const unsigned int target = 4u * (serial + 1u);
                unsigned int v = __hip_atomic_load(cntn, __ATOMIC_ACQUIRE, __HIP_MEMORY_SCOPE_AGENT);
                long guard = 0;
                while (v < target && guard < (1L << 24)) {
                    __builtin_amdgcn_s_sleep(1);
                    v = __hip_atomic_load(cntn, __ATOMIC_ACQUIRE, __HIP_MEMORY_SCOPE_AGENT);
                    ++guard;
                }
            }
            __syncthreads();
            // all 4 gates' parity slots visible; redundantly update h,c
            for (int r = tid; r < 300; r += 256) {
                const float zi = __hip_atomic_load(&zb[(0 + par) * 304 + r], __ATOMIC_RELAXED, __HIP_MEMORY_SCOPE_AGENT);
                const float zf = __hip_atomic_load(&zb[(2 + par) * 304 + r], __ATOMIC_RELAXED, __HIP_MEMORY_SCOPE_AGENT);
                const float zg = __hip_atomic_load(&zb[(4 + par) * 304 + r], __ATOMIC_RELAXED, __HIP_MEMORY_SCOPE_AGENT);
                const float zo = __hip_atomic_load(&zb[(6 + par) * 304 + r], __ATOMIC_RELAXED, __HIP_MEMORY_SCOPE_AGENT);
                const float cc = sigf(zf) * c_s[r] + sigf(zi) * tanhf(zg);
                c_s[r] = cc;
                h_s[r] = sigf(zo) * tanhf(cc);
            }
            __syncthreads();
            ++serial;
        }
        if (g == 0)
            for (int r = tid; r < 300; r += 256)
                hs[((size_t)(n * T_ + t)) * 300 + r] = h_s[r];
    }
    if (g == 0)
        for (int r = tid; r < 300; r += 256) {
            hc[n * 600 + r] = h_s[r];
            hc[n * 600 + 300 + r] = c_s[r];
        }
}

// ---------------------------------------------------------------------------
// Fusion head collapse: w = W2@W1 (492 weights), c0 = W2.b1 + b2 (wbuf[500]).
// ---------------------------------------------------------------------------
__global__ void wprep(const float* __restrict__ W1, const float* __restrict__ b1,
                      const float* __restrict__ W2, const float* __restrict__ b2,
                      float* __restrict__ wbuf)
{
    const int j = threadIdx.x;
    if (j < 492) {
        float a = 0.0f;
        for (int r = 0; r < 256; ++r) a += W2[r] * W1[r * 492 + j];
        wbuf[j] = a;
    } else if (j == 492) {
        float a = 0.0f;
        for (int r = 0; r < 256; ++r) a += W2[r] * b1[r];
        wbuf[500] = a + b2[0];
    }
}

// ---------------------------------------------------------------------------
// Output. CRITICAL: the reference does hs.reshape(n,t,h) on (T,N,h)-ordered
// scan output WITHOUT transposing — fused[i,j] = hs_scan[i*4 + j//64, j%64].
// We store hs as [n][t][h] (= hs_scan[t,n]), so gather from
// (n_src = j&63, t_src = i*4 + (j>>6)).
// ---------------------------------------------------------------------------
__global__ void out_kernel(const float* __restrict__ wbuf,
                           const float* __restrict__ hsL, const float* __restrict__ hsA,
                           const float* __restrict__ hsI,
                           const float* __restrict__ lmask, float* __restrict__ out)
{
    const int i = blockIdx.x;    // output n
    const int j = threadIdx.x;   // output t
    const int nn = j & 63;             // source sample
    const int tt = i * 4 + (j >> 6);   // source time
    const size_t src = (size_t)nn * T_ + tt;
    float acc = wbuf[500];
    const float4* hl = (const float4*)(hsL + src * HL);
#pragma unroll
    for (int u = 0; u < HL / 4; ++u) {
        const float4 h4 = hl[u];
        const float4 w4 = *(const float4*)&wbuf[4 * u];
        acc += h4.x * w4.x + h4.y * w4.y + h4.z * w4.z + h4.w * w4.w;
    }
    const float4* ha = (const float4*)(hsA + src * HA);
#pragma unroll
    for (int u = 0; u < HA / 4; ++u) {
        const float4 h4 = ha[u];
        const float4 w4 = *(const float4*)&wbuf[300 + 4 * u];
        acc += h4.x * w4.x + h4.y * w4.y + h4.z * w4.z + h4.w * w4.w;
    }
    const float4* hi = (const float4*)(hsI + src * HI);
#pragma unroll
    for (int u = 0; u < HI / 4; ++u) {
        const float4 h4 = hi[u];
        const float4 w4 = *(const float4*)&wbuf[364 + 4 * u];
        acc += h4.x * w4.x + h4.y * w4.y + h4.z * w4.z + h4.w * w4.w;
    }
    const size_t nt = (size_t)i * T_ + j;
    out[nt] = acc * lmask[nt];
}

// ---------------------------------------------------------------------------
extern "C" void kernel_launch(void* const* d_in, const int* in_sizes, int n_in,
                              void* d_out, int out_size, void* d_ws, size_t ws_size,
                              hipStream_t stream)
{
    (void)in_sizes; (void)n_in;
    const float* xL   = (const float*)d_in[0];
    const void*  mL   = d_in[1];
    const float* WihL = (const float*)d_in[2];
    const float* WhhL = (const float*)d_in[3];
    const float* bihL = (const float*)d_in[4];
    const float* bhhL = (const float*)d_in[5];
    const float* xA   = (const float*)d_in[6];
    const void*  mA   = d_in[7];
    const float* WihA = (const float*)d_in[8];
    const float* WhhA = (const float*)d_in[9];
    const float* bihA = (const float*)d_in[10];
    const float* bhhA = (const float*)d_in[11];
    const float* xI   = (const float*)d_in[12];
    const void*  mI   = d_in[13];
    const float* WihI = (const float*)d_in[14];
    const float* WhhI = (const float*)d_in[15];
    const float* bihI = (const float*)d_in[16];
    const float* bhhI = (const float*)d_in[17];
    const int*   seqlen = (const int*)d_in[18];
    const float* lmask  = (const float*)d_in[19];
    const float* W1 = (const float*)d_in[20];
    const float* b1 = (const float*)d_in[21];
    const float* W2 = (const float*)d_in[22];
    const float* b2 = (const float*)d_in[23];
    float* out = (float*)d_out;
    float* ws  = (float*)d_ws;

    // workspace layout
    unsigned int* cnt = (unsigned int*)d_ws;        // [0..64) u32
    int* modep = (int*)d_ws + 64;                   // [64] i32
    size_t off = 128;                               // floats
    float* wbuf = ws + off; off += 512;
    float* hsL = ws + off; off += (size_t)N_ * T_ * HL;
    float* hsA = ws + off; off += (size_t)N_ * T_ * HA;
    float* hsI = ws + off; off += (size_t)N_ * T_ * HI;
    float* hcL = ws + off; off += (size_t)N_ * 2 * HL;
    float* hcA = ws + off; off += (size_t)N_ * 2 * HA;
    float* hcI = ws + off; off += (size_t)N_ * 2 * HI;
    float* zbuf = ws + off; off += (size_t)N_ * 8 * 304;

    // largest t-chunk whose xproj buffers fit in remaining workspace
    int Tc = T_;
    while (Tc > 1 &&
           (off + (size_t)N_ * Tc * K_ * (H4L + H4A + H4I)) * sizeof(float) > ws_size)
        Tc >>= 1;
    if ((off + (size_t)N_ * Tc * K_ * (H4L + H4A + H4I)) * sizeof(float) > ws_size) {
        hipMemsetAsync(d_out, 0, (size_t)out_size * sizeof(float), stream);
        return;
    }
    float* xzL = ws + off; off += (size_t)N_ * Tc * K_ * H4L;
    float* xzA = ws + off; off += (size_t)N_ * Tc * K_ * H4A;
    float* xzI = ws + off; off += (size_t)N_ * Tc * K_ * H4I;

    mask_mode_detect<<<1, 256, 0, stream>>>((const unsigned int*)mL, modep);
    wprep<<<1, 512, 0, stream>>>(W1, b1, W2, b2, wbuf);

    const int My = (N_ * Tc * K_) / 64;
    for (int t0 = 0; t0 < T_; t0 += Tc) {
        gemm_xz<<<dim3((H4L + 63) / 64, My), 256, 0, stream>>>(
            xL, WihL, bihL, bhhL, seqlen, xzL, DL, H4L, Tc, t0);
        gemm_xz<<<dim3((H4A + 63) / 64, My), 256, 0, stream>>>(
            xA, WihA, bihA, bhhA, seqlen, xzA, DA, H4A, Tc, t0);
        gemm_xz<<<dim3((H4I + 63) / 64, My), 256, 0, stream>>>(
            xI, WihI, bihI, bhhI, seqlen, xzI, DI, H4I, Tc, t0);
        recur_small<<<2 * N_, 512, 0, stream>>>(
            WhhA, WhhI, mA, mI, modep, seqlen, xzA, xzI, hsA, hsI, hcA, hcI, Tc, t0);
        hipMemsetAsync(cnt, 0, 64 * sizeof(unsigned int), stream);
        recur_ling<<<4 * N_, 256, 0, stream>>>(
            WhhL, mL, modep, seqlen, xzL, hsL, hcL, zbuf, cnt, Tc, t0);
    }
    out_kernel<<<N_, T_, 0, stream>>>(wbuf, hsL, hsA, hsI, lmask, out);
}

// Round 4
// 6308.214 us; speedup vs baseline: 1.0222x; 1.0222x over previous
//
#include <hip/hip_runtime.h>
#include <hip/hip_bf16.h>
#include <stdint.h>

// Problem dims
#define N_ 64
#define T_ 256
#define K_ 4

#define DL 300
#define HL 300
#define H4L 1200

#define DA 88
#define HA 64
#define H4A 256

#define DI 128
#define HI 128
#define H4I 512

typedef __hip_bfloat16 bf16;

__device__ __forceinline__ float sigf(float x) { return 1.0f / (1.0f + expf(-x)); }

// Mask dtype detected at runtime: 0 = int32, 1 = uint8, 2 = float32.
__device__ __forceinline__ int read_mask(const void* m, size_t idx, int mode) {
    if (mode == 0) return ((const int*)m)[idx];
    if (mode == 1) return (int)((const unsigned char*)m)[idx];
    return ((const float*)m)[idx] != 0.0f;
}

__global__ void mask_mode_detect(const unsigned int* __restrict__ m, int* __restrict__ modep) {
    __shared__ unsigned int f[2];
    if (threadIdx.x == 0) { f[0] = 0u; f[1] = 0u; }
    __syncthreads();
    unsigned int gt1 = 0, f32one = 0;
    for (int i = threadIdx.x; i < 4096; i += 256) {
        const unsigned int v = m[i];
        if (v > 1u) gt1 = 1u;
        if (v == 0x3F800000u) f32one = 1u;
    }
    if (gt1) atomicOr(&f[0], 1u);
    if (f32one) atomicOr(&f[1], 1u);
    __syncthreads();
    if (threadIdx.x == 0) modep[0] = f[0] ? (f[1] ? 2 : 1) : 0;
}

// ---------------------------------------------------------------------------
// xproj GEMM: XZ[r][j] = sum_d Xrow(r)[d] * W[j][d] + bih[j] + bhh[j]
// r = (n*Tc + tt)*4 + k within the current t-chunk; tile skipped if all rows
// have t >= seq_len[n].
// ---------------------------------------------------------------------------
__global__ __launch_bounds__(256) void gemm_xz(
    const float* __restrict__ X, const float* __restrict__ W,
    const float* __restrict__ bih, const float* __restrict__ bhh,
    const int* __restrict__ seqlen,
    float* __restrict__ XZ,
    int D, int H4, int Tc, int t0)
{
    __shared__ __align__(16) float As[16][68];
    __shared__ __align__(16) float Bs[16][68];
    const int tid = threadIdx.x;
    const int m0 = blockIdx.y * 64;
    const int j0 = blockIdx.x * 64;
    const int Tc4 = Tc * 4;

    int act = 0;
    if (tid < 64) {
        const int rr = m0 + tid;
        const int n = rr / Tc4;
        const int ttt = (rr % Tc4) >> 2;
        act = (t0 + ttt) < seqlen[n];
    }
    if (!__syncthreads_or(act)) return;

    const int lc = tid & 15;
    const int lr = tid >> 4;
    const float* arow[4];
#pragma unroll
    for (int i = 0; i < 4; ++i) {
        const int rr = m0 + lr + 16 * i;
        const int n = rr / Tc4;
        const int ttt = (rr % Tc4) >> 2;
        const int k = rr & 3;
        arow[i] = X + ((size_t)((n * T_ + t0 + ttt) * 4 + k)) * D;
    }
    const int ty = tid >> 4;
    const int tx = tid & 15;
    float acc[4][4] = {};
    const int nkt = (D + 15) >> 4;
    for (int kt = 0; kt < nkt; ++kt) {
        const int d = kt * 16 + lc;
#pragma unroll
        for (int i = 0; i < 4; ++i) {
            As[lc][lr + 16 * i] = (d < D) ? arow[i][d] : 0.0f;
            const int jr = j0 + lr + 16 * i;
            Bs[lc][lr + 16 * i] = (d < D && jr < H4) ? W[(size_t)jr * D + d] : 0.0f;
        }
        __syncthreads();
#pragma unroll
        for (int kk = 0; kk < 16; ++kk) {
            const float4 av = *(const float4*)&As[kk][ty * 4];
            const float4 bv = *(const float4*)&Bs[kk][tx * 4];
            acc[0][0] += av.x * bv.x; acc[0][1] += av.x * bv.y; acc[0][2] += av.x * bv.z; acc[0][3] += av.x * bv.w;
            acc[1][0] += av.y * bv.x; acc[1][1] += av.y * bv.y; acc[1][2] += av.y * bv.z; acc[1][3] += av.y * bv.w;
            acc[2][0] += av.z * bv.x; acc[2][1] += av.z * bv.y; acc[2][2] += av.z * bv.z; acc[2][3] += av.z * bv.w;
            acc[3][0] += av.w * bv.x; acc[3][1] += av.w * bv.y; acc[3][2] += av.w * bv.z; acc[3][3] += av.w * bv.w;
        }
        __syncthreads();
    }
    const int col = j0 + tx * 4;
    if (col < H4) {
        const float4 bi = *(const float4*)&bih[col];
        const float4 bh = *(const float4*)&bhh[col];
        const float bx = bi.x + bh.x, by = bi.y + bh.y, bz = bi.z + bh.z, bw = bi.w + bh.w;
#pragma unroll
        for (int i = 0; i < 4; ++i) {
            const int rr = m0 + ty * 4 + i;
            float4 v;
            v.x = acc[i][0] + bx; v.y = acc[i][1] + by; v.z = acc[i][2] + bz; v.w = acc[i][3] + bw;
            *(float4*)&XZ[(size_t)rr * H4 + col] = v;
        }
    }
}

// ---------------------------------------------------------------------------
// Image + acoustic recurrences. 128 blocks x 512 threads. hs output in bf16.
// ---------------------------------------------------------------------------
__global__ __launch_bounds__(512, 2) void recur_small(
    const float* __restrict__ WhhA, const float* __restrict__ WhhI,
    const void* __restrict__ mA, const void* __restrict__ mI,
    const int* __restrict__ modep,
    const int* __restrict__ seqlen,
    const float* __restrict__ xzA, const float* __restrict__ xzI,
    bf16* __restrict__ hsA, bf16* __restrict__ hsI,
    float* __restrict__ hcA, float* __restrict__ hcI,
    int Tc, int t0)
{
    __shared__ __align__(16) float h_s[128];
    __shared__ __align__(16) float c_s[128];
    __shared__ __align__(16) float z_s[512];
    const int tid = threadIdx.x;
    const int mode = modep[0];

    if (blockIdx.x < N_) {
        // ---------------- image ----------------
        const int n = blockIdx.x;
        const int seqn = seqlen[n];
        float w[128];
        {
            const float4* wp = (const float4*)(WhhI + (size_t)tid * 128);
#pragma unroll
            for (int jj = 0; jj < 32; ++jj) {
                const float4 v = wp[jj];
                w[4 * jj] = v.x; w[4 * jj + 1] = v.y; w[4 * jj + 2] = v.z; w[4 * jj + 3] = v.w;
            }
        }
        if (tid < 128) {
            if (t0 == 0) { h_s[tid] = 0.0f; c_s[tid] = 0.0f; }
            else { h_s[tid] = hcI[n * 256 + tid]; c_s[tid] = hcI[n * 256 + 128 + tid]; }
        }
        __syncthreads();
#pragma unroll 1
        for (int tt = 0; tt < Tc; ++tt) {
            const int t = t0 + tt;
            if (t >= seqn) {
                if (tid < 128) hsI[((size_t)(n * T_ + t)) * 128 + tid] = __float2bfloat16(0.0f);
                continue;
            }
            const size_t xbase = ((size_t)((n * Tc + tt) * 4)) * 512;
            const size_t mbase = (size_t)(n * T_ + t) * 4;
#pragma unroll 1
            for (int k = 0; k < 4; ++k) {
                if (!read_mask(mI, mbase + k, mode)) continue;
                float acc = xzI[xbase + k * 512 + tid];
                const float4* hp = (const float4*)h_s;
#pragma unroll
                for (int jj = 0; jj < 32; ++jj) {
                    const float4 hv = hp[jj];
                    acc += w[4 * jj] * hv.x + w[4 * jj + 1] * hv.y
                         + w[4 * jj + 2] * hv.z + w[4 * jj + 3] * hv.w;
                }
                z_s[tid] = acc;
                __syncthreads();
                if (tid < 128) {
                    const float zi = z_s[tid], zf = z_s[128 + tid];
                    const float zg = z_s[256 + tid], zo = z_s[384 + tid];
                    const float cc = sigf(zf) * c_s[tid] + sigf(zi) * tanhf(zg);
                    c_s[tid] = cc;
                    h_s[tid] = sigf(zo) * tanhf(cc);
                }
                __syncthreads();
            }
            if (tid < 128) hsI[((size_t)(n * T_ + t)) * 128 + tid] = __float2bfloat16(h_s[tid]);
        }
        if (tid < 128) { hcI[n * 256 + tid] = h_s[tid]; hcI[n * 256 + 128 + tid] = c_s[tid]; }
    } else {
        // ---------------- acoustic ----------------
        const int n = blockIdx.x - N_;
        const int seqn = seqlen[n];
        float w[64];
        if (tid < 256) {
            const float4* wp = (const float4*)(WhhA + (size_t)tid * 64);
#pragma unroll
            for (int jj = 0; jj < 16; ++jj) {
                const float4 v = wp[jj];
                w[4 * jj] = v.x; w[4 * jj + 1] = v.y; w[4 * jj + 2] = v.z; w[4 * jj + 3] = v.w;
            }
        }
        if (tid < 64) {
            if (t0 == 0) { h_s[tid] = 0.0f; c_s[tid] = 0.0f; }
            else { h_s[tid] = hcA[n * 128 + tid]; c_s[tid] = hcA[n * 128 + 64 + tid]; }
        }
        __syncthreads();
#pragma unroll 1
        for (int tt = 0; tt < Tc; ++tt) {
            const int t = t0 + tt;
            if (t >= seqn) {
                if (tid < 64) hsA[((size_t)(n * T_ + t)) * 64 + tid] = __float2bfloat16(0.0f);
                continue;
            }
            const size_t xbase = ((size_t)((n * Tc + tt) * 4)) * 256;
            const size_t mbase = (size_t)(n * T_ + t) * 4;
#pragma unroll 1
            for (int k = 0; k < 4; ++k) {
                if (!read_mask(mA, mbase + k, mode)) continue;
                if (tid < 256) {
                    float acc = xzA[xbase + k * 256 + tid];
                    const float4* hp = (const float4*)h_s;
#pragma unroll
                    for (int jj = 0; jj < 16; ++jj) {
                        const float4 hv = hp[jj];
                        acc += w[4 * jj] * hv.x + w[4 * jj + 1] * hv.y
                             + w[4 * jj + 2] * hv.z + w[4 * jj + 3] * hv.w;
                    }
                    z_s[tid] = acc;
                }
                __syncthreads();
                if (tid < 64) {
                    const float zi = z_s[tid], zf = z_s[64 + tid];
                    const float zg = z_s[128 + tid], zo = z_s[192 + tid];
                    const float cc = sigf(zf) * c_s[tid] + sigf(zi) * tanhf(zg);
                    c_s[tid] = cc;
                    h_s[tid] = sigf(zo) * tanhf(cc);
                }
                __syncthreads();
            }
            if (tid < 64) hsA[((size_t)(n * T_ + t)) * 64 + tid] = __float2bfloat16(h_s[tid]);
        }
        if (tid < 64) { hcA[n * 128 + tid] = h_s[tid]; hcA[n * 128 + 64 + tid] = c_s[tid]; }
    }
}

// ---------------------------------------------------------------------------
// Linguistic recurrence: 4 blocks per sample (one per gate), 256 threads,
// gate's 300x300 Whh slice register-resident (375 w-regs/thread).
// Block swizzle co-locates all 4 gate blocks of a sample on ONE XCD
// (dispatch round-robins blockIdx across 8 XCDs): barrier atomics and zbuf
// exchange stay in that XCD's L2.
// Cross-block exchange: parity double-buffered zbuf[N][4][2][304], published
// with agent-scope atomic stores, consumed with agent-scope atomic loads;
// 4-block spin barrier on monotone counter cnt[n] (per-chunk slice, zeroed
// once per kernel_launch).
// ---------------------------------------------------------------------------
__global__ __launch_bounds__(256, 1) void recur_ling(
    const float* __restrict__ Whh,
    const void* __restrict__ mask,
    const int* __restrict__ modep,
    const int* __restrict__ seqlen,
    const float* __restrict__ xz,
    bf16* __restrict__ hs,
    float* __restrict__ hc,
    float* __restrict__ zbuf,       // [N][4][2][304]
    unsigned int* __restrict__ cnt, // [N] slice for THIS chunk, pre-zeroed
    int Tc, int t0)
{
    __shared__ float h_s[304];
    __shared__ float c_s[304];
    __shared__ float zp_s[1200];
    const int tid = threadIdx.x;
    // XCD-co-locating swizzle: blocks b with b%8==x land on XCD x.
    const int xcd = blockIdx.x & 7;
    const int idx = blockIdx.x >> 3;
    const int n = xcd * 8 + (idx >> 2);
    const int g = idx & 3;
    const int seqn = seqlen[n];
    const int mode = modep[0];

    // chunk = tid&3 owns cols [chunk*75, +75); rows r = (tid>>2) + 64*s.
    const int chunk = tid & 3;
    const int rb = tid >> 2;
    float w[5][75];
#pragma unroll
    for (int s = 0; s < 5; ++s) {
        int r = rb + 64 * s;
        if (r >= 300) r = 299;  // dup load; store side is guarded
        const float* wp = Whh + ((size_t)(g * 300 + r)) * 300 + chunk * 75;
#pragma unroll
        for (int j = 0; j < 75; ++j) w[s][j] = wp[j];
    }
    for (int r = tid; r < 300; r += 256) {
        if (t0 == 0) { h_s[r] = 0.0f; c_s[r] = 0.0f; }
        else { h_s[r] = hc[n * 600 + r]; c_s[r] = hc[n * 600 + 300 + r]; }
    }
    __syncthreads();

    unsigned int serial = 0;  // completed exchange rounds (identical across the 4 blocks)
    unsigned int* const cntn = &cnt[n];
    float* const pub = zbuf + ((size_t)(n * 4 + g)) * 2 * 304;
    float* const zb  = zbuf + (size_t)n * 8 * 304;   // slot (g,par) at (g*2+par)*304

#pragma unroll 1
    for (int tt = 0; tt < Tc; ++tt) {
        const int t = t0 + tt;
        if (t >= seqn) {
            if (g == 0)
                for (int r = tid; r < 300; r += 256)
                    hs[((size_t)(n * T_ + t)) * 300 + r] = __float2bfloat16(0.0f);
            continue;
        }
        const size_t mbase = (size_t)(n * T_ + t) * 4;
        const float* xzt = xz + ((size_t)((n * Tc + tt) * 4)) * 1200;
#pragma unroll 1
        for (int k = 0; k < 4; ++k) {
            if (!read_mask(mask, mbase + k, mode)) continue;
            const int par = (int)(serial & 1u);
            float a0 = 0.f, a1 = 0.f, a2 = 0.f, a3 = 0.f, a4 = 0.f;
#pragma unroll
            for (int j = 0; j < 75; ++j) {
                const float hv = h_s[chunk * 75 + j];  // 4 addrs/wave: broadcast
                a0 += w[0][j] * hv;
                a1 += w[1][j] * hv;
                a2 += w[2][j] * hv;
                a3 += w[3][j] * hv;
                a4 += w[4][j] * hv;
            }
            zp_s[chunk * 300 + rb]       = a0;
            zp_s[chunk * 300 + rb + 64]  = a1;
            zp_s[chunk * 300 + rb + 128] = a2;
            zp_s[chunk * 300 + rb + 192] = a3;
            if (rb < 44) zp_s[chunk * 300 + rb + 256] = a4;
            __syncthreads();
            // reduce 4 col-chunks + xz slice; publish this gate's z (parity slot)
            const float* xg = xzt + k * 1200 + g * 300;
            for (int r = tid; r < 300; r += 256) {
                const float z = xg[r] + zp_s[r] + zp_s[300 + r] + zp_s[600 + r] + zp_s[900 + r];
                __hip_atomic_store(&pub[par * 304 + r], z, __ATOMIC_RELAXED, __HIP_MEMORY_SCOPE_AGENT);
            }
            __syncthreads();
            if (tid == 0) {
                __hip_atomic_fetch_add(cntn, 1u, __ATOMIC_RELEASE, __HIP_MEMORY_SCOPE_AGENT);
                const unsigned int target = 4u * (serial + 1u);
                unsigned int v = __hip_atomic_load(cntn, __ATOMIC_ACQUIRE, __HIP_MEMORY_SCOPE_AGENT);
                long guard = 0;
                while (v < target && guard < (1L << 24)) {
                    __builtin_amdgcn_s_sleep(1);
                    v = __hip_atomic_load(cntn, __ATOMIC_ACQUIRE, __HIP_MEMORY_SCOPE_AGENT);
                    ++guard;
                }
            }
            __syncthreads();
            // all 4 gates' parity slots visible; redundantly update h,c
            for (int r = tid; r < 300; r += 256) {
                const float zi = __hip_atomic_load(&zb[(0 + par) * 304 + r], __ATOMIC_RELAXED, __HIP_MEMORY_SCOPE_AGENT);
                const float zf = __hip_atomic_load(&zb[(2 + par) * 304 + r], __ATOMIC_RELAXED, __HIP_MEMORY_SCOPE_AGENT);
                const float zg = __hip_atomic_load(&zb[(4 + par) * 304 + r], __ATOMIC_RELAXED, __HIP_MEMORY_SCOPE_AGENT);
                const float zo = __hip_atomic_load(&zb[(6 + par) * 304 + r], __ATOMIC_RELAXED, __HIP_MEMORY_SCOPE_AGENT);
                const float cc = sigf(zf) * c_s[r] + sigf(zi) * tanhf(zg);
                c_s[r] = cc;
                h_s[r] = sigf(zo) * tanhf(cc);
            }
            __syncthreads();
            ++serial;
        }
        if (g == 0)
            for (int r = tid; r < 300; r += 256)
                hs[((size_t)(n * T_ + t)) * 300 + r] = __float2bfloat16(h_s[r]);
    }
    if (g == 0)
        for (int r = tid; r < 300; r += 256) {
            hc[n * 600 + r] = h_s[r];
            hc[n * 600 + 300 + r] = c_s[r];
        }
}

// ---------------------------------------------------------------------------
// Fusion head collapse: w = W2@W1 (492 weights), c0 = W2.b1 + b2 (wbuf[500]).
// ---------------------------------------------------------------------------
__global__ void wprep(const float* __restrict__ W1, const float* __restrict__ b1,
                      const float* __restrict__ W2, const float* __restrict__ b2,
                      float* __restrict__ wbuf)
{
    const int j = threadIdx.x;
    if (j < 492) {
        float a = 0.0f;
        for (int r = 0; r < 256; ++r) a += W2[r] * W1[r * 492 + j];
        wbuf[j] = a;
    } else if (j == 492) {
        float a = 0.0f;
        for (int r = 0; r < 256; ++r) a += W2[r] * b1[r];
        wbuf[500] = a + b2[0];
    }
}

// ---------------------------------------------------------------------------
// Output. The reference does hs.reshape(n,t,h) on (T,N,h)-ordered scan output
// WITHOUT transposing — fused[i,j] = hs_scan[i*4 + j//64, j%64]. We store hs
// as [n][t][h], so gather from (n_src = j&63, t_src = i*4 + (j>>6)).
// hs is bf16; unpack via uint2 (4 elems / 8B load).
// ---------------------------------------------------------------------------
__device__ __forceinline__ float bflo(unsigned int u) { return __uint_as_float(u << 16); }
__device__ __forceinline__ float bfhi(unsigned int u) { return __uint_as_float(u & 0xFFFF0000u); }

__global__ void out_kernel(const float* __restrict__ wbuf,
                           const ushort* __restrict__ hsL, const ushort* __restrict__ hsA,
                           const ushort* __restrict__ hsI,
                           const float* __restrict__ lmask, float* __restrict__ out)
{
    const int i = blockIdx.x;    // output n
    const int j = threadIdx.x;   // output t
    const int nn = j & 63;             // source sample
    const int tt = i * 4 + (j >> 6);   // source time
    const size_t src = (size_t)nn * T_ + tt;
    float acc = wbuf[500];
    const uint2* hl = (const uint2*)(hsL + src * HL);
#pragma unroll
    for (int u = 0; u < HL / 4; ++u) {
        const uint2 v = hl[u];
        const float4 w4 = *(const float4*)&wbuf[4 * u];
        acc += bflo(v.x) * w4.x + bfhi(v.x) * w4.y + bflo(v.y) * w4.z + bfhi(v.y) * w4.w;
    }
    const uint2* ha = (const uint2*)(hsA + src * HA);
#pragma unroll
    for (int u = 0; u < HA / 4; ++u) {
        const uint2 v = ha[u];
        const float4 w4 = *(const float4*)&wbuf[300 + 4 * u];
        acc += bflo(v.x) * w4.x + bfhi(v.x) * w4.y + bflo(v.y) * w4.z + bfhi(v.y) * w4.w;
    }
    const uint2* hi = (const uint2*)(hsI + src * HI);
#pragma unroll
    for (int u = 0; u < HI / 4; ++u) {
        const uint2 v = hi[u];
        const float4 w4 = *(const float4*)&wbuf[364 + 4 * u];
        acc += bflo(v.x) * w4.x + bfhi(v.x) * w4.y + bflo(v.y) * w4.z + bfhi(v.y) * w4.w;
    }
    const size_t nt = (size_t)i * T_ + j;
    out[nt] = acc * lmask[nt];
}

// ---------------------------------------------------------------------------
extern "C" void kernel_launch(void* const* d_in, const int* in_sizes, int n_in,
                              void* d_out, int out_size, void* d_ws, size_t ws_size,
                              hipStream_t stream)
{
    (void)in_sizes; (void)n_in;
    const float* xL   = (const float*)d_in[0];
    const void*  mL   = d_in[1];
    const float* WihL = (const float*)d_in[2];
    const float* WhhL = (const float*)d_in[3];
    const float* bihL = (const float*)d_in[4];
    const float* bhhL = (const float*)d_in[5];
    const float* xA   = (const float*)d_in[6];
    const void*  mA   = d_in[7];
    const float* WihA = (const float*)d_in[8];
    const float* WhhA = (const float*)d_in[9];
    const float* bihA = (const float*)d_in[10];
    const float* bhhA = (const float*)d_in[11];
    const float* xI   = (const float*)d_in[12];
    const void*  mI   = d_in[13];
    const float* WihI = (const float*)d_in[14];
    const float* WhhI = (const float*)d_in[15];
    const float* bihI = (const float*)d_in[16];
    const float* bhhI = (const float*)d_in[17];
    const int*   seqlen = (const int*)d_in[18];
    const float* lmask  = (const float*)d_in[19];
    const float* W1 = (const float*)d_in[20];
    const float* b1 = (const float*)d_in[21];
    const float* W2 = (const float*)d_in[22];
    const float* b2 = (const float*)d_in[23];
    float* out = (float*)d_out;

    // Byte-accurate workspace layout, 64B aligned blocks.
    char* base = (char*)d_ws;
    size_t off = 0;
    auto take = [&](size_t bytes) -> char* {
        char* p = base + off;
        off += (bytes + 63) & ~(size_t)63;
        return p;
    };
    unsigned int* cnt = (unsigned int*)take(256 * 64 * sizeof(unsigned int)); // per-chunk slices
    int*   modep = (int*)take(64);
    float* wbuf  = (float*)take(512 * sizeof(float));
    float* hcL   = (float*)take((size_t)N_ * 2 * HL * sizeof(float));
    float* hcA   = (float*)take((size_t)N_ * 2 * HA * sizeof(float));
    float* hcI   = (float*)take((size_t)N_ * 2 * HI * sizeof(float));
    float* zbuf  = (float*)take((size_t)N_ * 8 * 304 * sizeof(float));
    bf16*  hsL   = (bf16*)take((size_t)N_ * T_ * HL * sizeof(bf16));
    bf16*  hsA   = (bf16*)take((size_t)N_ * T_ * HA * sizeof(bf16));
    bf16*  hsI   = (bf16*)take((size_t)N_ * T_ * HI * sizeof(bf16));

    // largest t-chunk whose xz buffers fit in the remaining workspace
    const size_t xz_per_tc = (size_t)N_ * K_ * (H4L + H4A + H4I) * sizeof(float);
    int Tc = T_;
    while (Tc > 1 && off + (size_t)Tc * xz_per_tc + 256 > ws_size) Tc >>= 1;
    if (off + (size_t)Tc * xz_per_tc + 256 > ws_size) {
        hipMemsetAsync(d_out, 0, (size_t)out_size * sizeof(float), stream);
        return;
    }
    float* xzL = (float*)take((size_t)N_ * Tc * K_ * H4L * sizeof(float));
    float* xzA = (float*)take((size_t)N_ * Tc * K_ * H4A * sizeof(float));
    float* xzI = (float*)take((size_t)N_ * Tc * K_ * H4I * sizeof(float));

    const int nchunks = T_ / Tc;
    hipMemsetAsync(cnt, 0, (size_t)nchunks * 64 * sizeof(unsigned int), stream);
    mask_mode_detect<<<1, 256, 0, stream>>>((const unsigned int*)mL, modep);
    wprep<<<1, 512, 0, stream>>>(W1, b1, W2, b2, wbuf);

    const int My = (N_ * Tc * K_) / 64;
    for (int c = 0; c < nchunks; ++c) {
        const int t0 = c * Tc;
        gemm_xz<<<dim3((H4L + 63) / 64, My), 256, 0, stream>>>(
            xL, WihL, bihL, bhhL, seqlen, xzL, DL, H4L, Tc, t0);
        gemm_xz<<<dim3((H4A + 63) / 64, My), 256, 0, stream>>>(
            xA, WihA, bihA, bhhA, seqlen, xzA, DA, H4A, Tc, t0);
        gemm_xz<<<dim3((H4I + 63) / 64, My), 256, 0, stream>>>(
            xI, WihI, bihI, bhhI, seqlen, xzI, DI, H4I, Tc, t0);
        recur_small<<<2 * N_, 512, 0, stream>>>(
            WhhA, WhhI, mA, mI, modep, seqlen, xzA, xzI, hsA, hsI, hcA, hcI, Tc, t0);
        recur_ling<<<4 * N_, 256, 0, stream>>>(
            WhhL, mL, modep, seqlen, xzL, hsL, hcL, zbuf, cnt + (size_t)c * 64, Tc, t0);
    }
    out_kernel<<<N_, T_, 0, stream>>>(wbuf, (const ushort*)hsL, (const ushort*)hsA,
                                      (const ushort*)hsI, lmask, out);
}

// Round 5
// 6132.404 us; speedup vs baseline: 1.0515x; 1.0287x over previous
//
#include <hip/hip_runtime.h>
#include <hip/hip_bf16.h>
#include <stdint.h>

// Problem dims
#define N_ 64
#define T_ 256
#define K_ 4

#define DL 300
#define HL 300
#define H4L 1200

#define DA 88
#define HA 64
#define H4A 256

#define DI 128
#define HI 128
#define H4I 512

typedef __hip_bfloat16 bf16;

__device__ __forceinline__ float sigf(float x) { return 1.0f / (1.0f + expf(-x)); }

// Mask dtype detected at runtime: 0 = int32, 1 = uint8, 2 = float32.
__device__ __forceinline__ int read_mask(const void* m, size_t idx, int mode) {
    if (mode == 0) return ((const int*)m)[idx];
    if (mode == 1) return (int)((const unsigned char*)m)[idx];
    return ((const float*)m)[idx] != 0.0f;
}

__global__ void mask_mode_detect(const unsigned int* __restrict__ m, int* __restrict__ modep) {
    __shared__ unsigned int f[2];
    if (threadIdx.x == 0) { f[0] = 0u; f[1] = 0u; }
    __syncthreads();
    unsigned int gt1 = 0, f32one = 0;
    for (int i = threadIdx.x; i < 4096; i += 256) {
        const unsigned int v = m[i];
        if (v > 1u) gt1 = 1u;
        if (v == 0x3F800000u) f32one = 1u;
    }
    if (gt1) atomicOr(&f[0], 1u);
    if (f32one) atomicOr(&f[1], 1u);
    __syncthreads();
    if (threadIdx.x == 0) modep[0] = f[0] ? (f[1] ? 2 : 1) : 0;
}

// ---------------------------------------------------------------------------
// xproj GEMM: XZ[r][j] = sum_d Xrow(r)[d] * W[j][d] + bih[j] + bhh[j]
// ---------------------------------------------------------------------------
__global__ __launch_bounds__(256) void gemm_xz(
    const float* __restrict__ X, const float* __restrict__ W,
    const float* __restrict__ bih, const float* __restrict__ bhh,
    const int* __restrict__ seqlen,
    float* __restrict__ XZ,
    int D, int H4, int Tc, int t0)
{
    __shared__ __align__(16) float As[16][68];
    __shared__ __align__(16) float Bs[16][68];
    const int tid = threadIdx.x;
    const int m0 = blockIdx.y * 64;
    const int j0 = blockIdx.x * 64;
    const int Tc4 = Tc * 4;

    int act = 0;
    if (tid < 64) {
        const int rr = m0 + tid;
        const int n = rr / Tc4;
        const int ttt = (rr % Tc4) >> 2;
        act = (t0 + ttt) < seqlen[n];
    }
    if (!__syncthreads_or(act)) return;

    const int lc = tid & 15;
    const int lr = tid >> 4;
    const float* arow[4];
#pragma unroll
    for (int i = 0; i < 4; ++i) {
        const int rr = m0 + lr + 16 * i;
        const int n = rr / Tc4;
        const int ttt = (rr % Tc4) >> 2;
        const int k = rr & 3;
        arow[i] = X + ((size_t)((n * T_ + t0 + ttt) * 4 + k)) * D;
    }
    const int ty = tid >> 4;
    const int tx = tid & 15;
    float acc[4][4] = {};
    const int nkt = (D + 15) >> 4;
    for (int kt = 0; kt < nkt; ++kt) {
        const int d = kt * 16 + lc;
#pragma unroll
        for (int i = 0; i < 4; ++i) {
            As[lc][lr + 16 * i] = (d < D) ? arow[i][d] : 0.0f;
            const int jr = j0 + lr + 16 * i;
            Bs[lc][lr + 16 * i] = (d < D && jr < H4) ? W[(size_t)jr * D + d] : 0.0f;
        }
        __syncthreads();
#pragma unroll
        for (int kk = 0; kk < 16; ++kk) {
            const float4 av = *(const float4*)&As[kk][ty * 4];
            const float4 bv = *(const float4*)&Bs[kk][tx * 4];
            acc[0][0] += av.x * bv.x; acc[0][1] += av.x * bv.y; acc[0][2] += av.x * bv.z; acc[0][3] += av.x * bv.w;
            acc[1][0] += av.y * bv.x; acc[1][1] += av.y * bv.y; acc[1][2] += av.y * bv.z; acc[1][3] += av.y * bv.w;
            acc[2][0] += av.z * bv.x; acc[2][1] += av.z * bv.y; acc[2][2] += av.z * bv.z; acc[2][3] += av.z * bv.w;
            acc[3][0] += av.w * bv.x; acc[3][1] += av.w * bv.y; acc[3][2] += av.w * bv.z; acc[3][3] += av.w * bv.w;
        }
        __syncthreads();
    }
    const int col = j0 + tx * 4;
    if (col < H4) {
        const float4 bi = *(const float4*)&bih[col];
        const float4 bh = *(const float4*)&bhh[col];
        const float bx = bi.x + bh.x, by = bi.y + bh.y, bz = bi.z + bh.z, bw = bi.w + bh.w;
#pragma unroll
        for (int i = 0; i < 4; ++i) {
            const int rr = m0 + ty * 4 + i;
            float4 v;
            v.x = acc[i][0] + bx; v.y = acc[i][1] + by; v.z = acc[i][2] + bz; v.w = acc[i][3] + bw;
            *(float4*)&XZ[(size_t)rr * H4 + col] = v;
        }
    }
}

// ---------------------------------------------------------------------------
// Image + acoustic recurrences. 128 blocks x 512 threads. hs output in bf16.
// ---------------------------------------------------------------------------
__global__ __launch_bounds__(512, 2) void recur_small(
    const float* __restrict__ WhhA, const float* __restrict__ WhhI,
    const void* __restrict__ mA, const void* __restrict__ mI,
    const int* __restrict__ modep,
    const int* __restrict__ seqlen,
    const float* __restrict__ xzA, const float* __restrict__ xzI,
    bf16* __restrict__ hsA, bf16* __restrict__ hsI,
    float* __restrict__ hcA, float* __restrict__ hcI,
    int Tc, int t0)
{
    __shared__ __align__(16) float h_s[128];
    __shared__ __align__(16) float c_s[128];
    __shared__ __align__(16) float z_s[512];
    const int tid = threadIdx.x;
    const int mode = modep[0];

    if (blockIdx.x < N_) {
        // ---------------- image ----------------
        const int n = blockIdx.x;
        const int seqn = seqlen[n];
        float w[128];
        {
            const float4* wp = (const float4*)(WhhI + (size_t)tid * 128);
#pragma unroll
            for (int jj = 0; jj < 32; ++jj) {
                const float4 v = wp[jj];
                w[4 * jj] = v.x; w[4 * jj + 1] = v.y; w[4 * jj + 2] = v.z; w[4 * jj + 3] = v.w;
            }
        }
        if (tid < 128) {
            if (t0 == 0) { h_s[tid] = 0.0f; c_s[tid] = 0.0f; }
            else { h_s[tid] = hcI[n * 256 + tid]; c_s[tid] = hcI[n * 256 + 128 + tid]; }
        }
        __syncthreads();
#pragma unroll 1
        for (int tt = 0; tt < Tc; ++tt) {
            const int t = t0 + tt;
            if (t >= seqn) {
                if (tid < 128) hsI[((size_t)(n * T_ + t)) * 128 + tid] = __float2bfloat16(0.0f);
                continue;
            }
            const size_t xbase = ((size_t)((n * Tc + tt) * 4)) * 512;
            const size_t mbase = (size_t)(n * T_ + t) * 4;
#pragma unroll 1
            for (int k = 0; k < 4; ++k) {
                if (!read_mask(mI, mbase + k, mode)) continue;
                float acc = xzI[xbase + k * 512 + tid];
                const float4* hp = (const float4*)h_s;
#pragma unroll
                for (int jj = 0; jj < 32; ++jj) {
                    const float4 hv = hp[jj];
                    acc += w[4 * jj] * hv.x + w[4 * jj + 1] * hv.y
                         + w[4 * jj + 2] * hv.z + w[4 * jj + 3] * hv.w;
                }
                z_s[tid] = acc;
                __syncthreads();
                if (tid < 128) {
                    const float zi = z_s[tid], zf = z_s[128 + tid];
                    const float zg = z_s[256 + tid], zo = z_s[384 + tid];
                    const float cc = sigf(zf) * c_s[tid] + sigf(zi) * tanhf(zg);
                    c_s[tid] = cc;
                    h_s[tid] = sigf(zo) * tanhf(cc);
                }
                __syncthreads();
            }
            if (tid < 128) hsI[((size_t)(n * T_ + t)) * 128 + tid] = __float2bfloat16(h_s[tid]);
        }
        if (tid < 128) { hcI[n * 256 + tid] = h_s[tid]; hcI[n * 256 + 128 + tid] = c_s[tid]; }
    } else {
        // ---------------- acoustic ----------------
        const int n = blockIdx.x - N_;
        const int seqn = seqlen[n];
        float w[64];
        if (tid < 256) {
            const float4* wp = (const float4*)(WhhA + (size_t)tid * 64);
#pragma unroll
            for (int jj = 0; jj < 16; ++jj) {
                const float4 v = wp[jj];
                w[4 * jj] = v.x; w[4 * jj + 1] = v.y; w[4 * jj + 2] = v.z; w[4 * jj + 3] = v.w;
            }
        }
        if (tid < 64) {
            if (t0 == 0) { h_s[tid] = 0.0f; c_s[tid] = 0.0f; }
            else { h_s[tid] = hcA[n * 128 + tid]; c_s[tid] = hcA[n * 128 + 64 + tid]; }
        }
        __syncthreads();
#pragma unroll 1
        for (int tt = 0; tt < Tc; ++tt) {
            const int t = t0 + tt;
            if (t >= seqn) {
                if (tid < 64) hsA[((size_t)(n * T_ + t)) * 64 + tid] = __float2bfloat16(0.0f);
                continue;
            }
            const size_t xbase = ((size_t)((n * Tc + tt) * 4)) * 256;
            const size_t mbase = (size_t)(n * T_ + t) * 4;
#pragma unroll 1
            for (int k = 0; k < 4; ++k) {
                if (!read_mask(mA, mbase + k, mode)) continue;
                if (tid < 256) {
                    float acc = xzA[xbase + k * 256 + tid];
                    const float4* hp = (const float4*)h_s;
#pragma unroll
                    for (int jj = 0; jj < 16; ++jj) {
                        const float4 hv = hp[jj];
                        acc += w[4 * jj] * hv.x + w[4 * jj + 1] * hv.y
                             + w[4 * jj + 2] * hv.z + w[4 * jj + 3] * hv.w;
                    }
                    z_s[tid] = acc;
                }
                __syncthreads();
                if (tid < 64) {
                    const float zi = z_s[tid], zf = z_s[64 + tid];
                    const float zg = z_s[128 + tid], zo = z_s[192 + tid];
                    const float cc = sigf(zf) * c_s[tid] + sigf(zi) * tanhf(zg);
                    c_s[tid] = cc;
                    h_s[tid] = sigf(zo) * tanhf(cc);
                }
                __syncthreads();
            }
            if (tid < 64) hsA[((size_t)(n * T_ + t)) * 64 + tid] = __float2bfloat16(h_s[tid]);
        }
        if (tid < 64) { hcA[n * 128 + tid] = h_s[tid]; hcA[n * 128 + 64 + tid] = c_s[tid]; }
    }
}

// ---------------------------------------------------------------------------
// Linguistic recurrence: 4 blocks per sample (one per gate), 512 threads.
// ROUND-5 FIX: round 4 used 256 threads and needed 375 weight VGPRs/thread;
// compiler capped at 244 -> weights spilled to scratch, re-streamed every
// step (the observed 2.3ms/dispatch, VALUBusy 10%). Now 8 col-chunks x 38
// cols x 5 row-stripes = 190 weight VGPRs/thread under the 256-VGPR cap of
// __launch_bounds__(512,2): no spill, matvec runs from registers.
// LDS zp stride 308: chunk offsets map to 8 distinct banks (2-way max = free).
// Cross-block exchange unchanged: parity double-buffered zbuf[N][4][2][304],
// agent-scope atomics, 4-block spin barrier on cnt[n], XCD-co-located blocks.
// ---------------------------------------------------------------------------
__global__ __launch_bounds__(512, 2) void recur_ling(
    const float* __restrict__ Whh,
    const void* __restrict__ mask,
    const int* __restrict__ modep,
    const int* __restrict__ seqlen,
    const float* __restrict__ xz,
    bf16* __restrict__ hs,
    float* __restrict__ hc,
    float* __restrict__ zbuf,       // [N][4][2][304]
    unsigned int* __restrict__ cnt, // [N] slice for THIS chunk, pre-zeroed
    int Tc, int t0)
{
    __shared__ float h_s[304];      // padded; [300..303] stay 0
    __shared__ float c_s[304];
    __shared__ float zp_s[8 * 308];
    const int tid = threadIdx.x;
    // XCD-co-locating swizzle: all 4 gate blocks of a sample on one XCD.
    const int xcd = blockIdx.x & 7;
    const int idx = blockIdx.x >> 3;
    const int n = xcd * 8 + (idx >> 2);
    const int g = idx & 3;
    const int seqn = seqlen[n];
    const int mode = modep[0];

    // chunk = tid&7 owns cols [chunk*38, +38); rows r = (tid>>3) + 64*s.
    const int chunk = tid & 7;
    const int rb = tid >> 3;        // 0..63
    const int cj = chunk * 38;
    float w[5][38];
#pragma unroll
    for (int s = 0; s < 5; ++s) {
        const int r = rb + 64 * s;
        const bool rv = (r < 300);
        const float* wp = Whh + ((size_t)(g * 300 + (rv ? r : 0))) * 300;
#pragma unroll
        for (int j = 0; j < 38; ++j) {
            const int col = cj + j;
            w[s][j] = (rv && col < 300) ? wp[col] : 0.0f;
        }
    }
    for (int r = tid; r < 304; r += 512) {
        if (t0 == 0 || r >= 300) { h_s[r] = 0.0f; c_s[r] = 0.0f; }
        else { h_s[r] = hc[n * 600 + r]; c_s[r] = hc[n * 600 + 300 + r]; }
    }
    __syncthreads();

    unsigned int serial = 0;  // completed exchange rounds (same across 4 blocks)
    unsigned int* const cntn = &cnt[n];
    float* const pub = zbuf + ((size_t)(n * 4 + g)) * 2 * 304;
    float* const zb  = zbuf + (size_t)n * 8 * 304;   // slot (g,par) at (g*2+par)*304

#pragma unroll 1
    for (int tt = 0; tt < Tc; ++tt) {
        const int t = t0 + tt;
        if (t >= seqn) {
            if (g == 0 && tid < 300)
                hs[((size_t)(n * T_ + t)) * 300 + tid] = __float2bfloat16(0.0f);
            continue;
        }
        const size_t mbase = (size_t)(n * T_ + t) * 4;
        const float* xzt = xz + ((size_t)((n * Tc + tt) * 4)) * 1200;
#pragma unroll 1
        for (int k = 0; k < 4; ++k) {
            if (!read_mask(mask, mbase + k, mode)) continue;
            const int par = (int)(serial & 1u);
            float a0 = 0.f, a1 = 0.f, a2 = 0.f, a3 = 0.f, a4 = 0.f;
#pragma unroll
            for (int j = 0; j < 38; ++j) {
                const float hv = h_s[cj + j];   // 8 addrs/wave, 8-way broadcast
                a0 += w[0][j] * hv;
                a1 += w[1][j] * hv;
                a2 += w[2][j] * hv;
                a3 += w[3][j] * hv;
                a4 += w[4][j] * hv;
            }
            zp_s[chunk * 308 + rb]       = a0;
            zp_s[chunk * 308 + rb + 64]  = a1;
            zp_s[chunk * 308 + rb + 128] = a2;
            zp_s[chunk * 308 + rb + 192] = a3;
            if (rb < 44) zp_s[chunk * 308 + rb + 256] = a4;
            __syncthreads();
            // reduce 8 col-chunks + xz slice; publish this gate's z (parity slot)
            if (tid < 300) {
                const float* xg = xzt + k * 1200 + g * 300;
                float z = xg[tid];
#pragma unroll
                for (int c = 0; c < 8; ++c) z += zp_s[c * 308 + tid];
                __hip_atomic_store(&pub[par * 304 + tid], z, __ATOMIC_RELAXED, __HIP_MEMORY_SCOPE_AGENT);
            }
            __syncthreads();
            if (tid == 0) {
                __hip_atomic_fetch_add(cntn, 1u, __ATOMIC_RELEASE, __HIP_MEMORY_SCOPE_AGENT);
                const unsigned int target = 4u * (serial + 1u);
                unsigned int v = __hip_atomic_load(cntn, __ATOMIC_ACQUIRE, __HIP_MEMORY_SCOPE_AGENT);
                long guard = 0;
                while (v < target && guard < (1L << 24)) {
                    __builtin_amdgcn_s_sleep(1);
                    v = __hip_atomic_load(cntn, __ATOMIC_ACQUIRE, __HIP_MEMORY_SCOPE_AGENT);
                    ++guard;
                }
            }
            __syncthreads();
            // all 4 gates' parity slots visible; redundantly update h,c
            if (tid < 300) {
                const float zi = __hip_atomic_load(&zb[(0 + par) * 304 + tid], __ATOMIC_RELAXED, __HIP_MEMORY_SCOPE_AGENT);
                const float zf = __hip_atomic_load(&zb[(2 + par) * 304 + tid], __ATOMIC_RELAXED, __HIP_MEMORY_SCOPE_AGENT);
                const float zg = __hip_atomic_load(&zb[(4 + par) * 304 + tid], __ATOMIC_RELAXED, __HIP_MEMORY_SCOPE_AGENT);
                const float zo = __hip_atomic_load(&zb[(6 + par) * 304 + tid], __ATOMIC_RELAXED, __HIP_MEMORY_SCOPE_AGENT);
                const float cc = sigf(zf) * c_s[tid] + sigf(zi) * tanhf(zg);
                c_s[tid] = cc;
                h_s[tid] = sigf(zo) * tanhf(cc);
            }
            __syncthreads();
            ++serial;
        }
        if (g == 0 && tid < 300)
            hs[((size_t)(n * T_ + t)) * 300 + tid] = __float2bfloat16(h_s[tid]);
    }
    if (g == 0 && tid < 300) {
        hc[n * 600 + tid] = h_s[tid];
        hc[n * 600 + 300 + tid] = c_s[tid];
    }
}

// ---------------------------------------------------------------------------
// Fusion head collapse: w = W2@W1 (492 weights), c0 = W2.b1 + b2 (wbuf[500]).
// ---------------------------------------------------------------------------
__global__ void wprep(const float* __restrict__ W1, const float* __restrict__ b1,
                      const float* __restrict__ W2, const float* __restrict__ b2,
                      float* __restrict__ wbuf)
{
    const int j = threadIdx.x;
    if (j < 492) {
        float a = 0.0f;
        for (int r = 0; r < 256; ++r) a += W2[r] * W1[r * 492 + j];
        wbuf[j] = a;
    } else if (j == 492) {
        float a = 0.0f;
        for (int r = 0; r < 256; ++r) a += W2[r] * b1[r];
        wbuf[500] = a + b2[0];
    }
}

// ---------------------------------------------------------------------------
// Output. The reference does hs.reshape(n,t,h) on (T,N,h)-ordered scan output
// WITHOUT transposing — fused[i,j] = hs_scan[i*4 + j//64, j%64]. We store hs
// as [n][t][h], so gather from (n_src = j&63, t_src = i*4 + (j>>6)).
// ---------------------------------------------------------------------------
__device__ __forceinline__ float bflo(unsigned int u) { return __uint_as_float(u << 16); }
__device__ __forceinline__ float bfhi(unsigned int u) { return __uint_as_float(u & 0xFFFF0000u); }

__global__ void out_kernel(const float* __restrict__ wbuf,
                           const ushort* __restrict__ hsL, const ushort* __restrict__ hsA,
                           const ushort* __restrict__ hsI,
                           const float* __restrict__ lmask, float* __restrict__ out)
{
    const int i = blockIdx.x;    // output n
    const int j = threadIdx.x;   // output t
    const int nn = j & 63;             // source sample
    const int tt = i * 4 + (j >> 6);   // source time
    const size_t src = (size_t)nn * T_ + tt;
    float acc = wbuf[500];
    const uint2* hl = (const uint2*)(hsL + src * HL);
#pragma unroll
    for (int u = 0; u < HL / 4; ++u) {
        const uint2 v = hl[u];
        const float4 w4 = *(const float4*)&wbuf[4 * u];
        acc += bflo(v.x) * w4.x + bfhi(v.x) * w4.y + bflo(v.y) * w4.z + bfhi(v.y) * w4.w;
    }
    const uint2* ha = (const uint2*)(hsA + src * HA);
#pragma unroll
    for (int u = 0; u < HA / 4; ++u) {
        const uint2 v = ha[u];
        const float4 w4 = *(const float4*)&wbuf[300 + 4 * u];
        acc += bflo(v.x) * w4.x + bfhi(v.x) * w4.y + bflo(v.y) * w4.z + bfhi(v.y) * w4.w;
    }
    const uint2* hi = (const uint2*)(hsI + src * HI);
#pragma unroll
    for (int u = 0; u < HI / 4; ++u) {
        const uint2 v = hi[u];
        const float4 w4 = *(const float4*)&wbuf[364 + 4 * u];
        acc += bflo(v.x) * w4.x + bfhi(v.x) * w4.y + bflo(v.y) * w4.z + bfhi(v.y) * w4.w;
    }
    const size_t nt = (size_t)i * T_ + j;
    out[nt] = acc * lmask[nt];
}

// ---------------------------------------------------------------------------
extern "C" void kernel_launch(void* const* d_in, const int* in_sizes, int n_in,
                              void* d_out, int out_size, void* d_ws, size_t ws_size,
                              hipStream_t stream)
{
    (void)in_sizes; (void)n_in;
    const float* xL   = (const float*)d_in[0];
    const void*  mL   = d_in[1];
    const float* WihL = (const float*)d_in[2];
    const float* WhhL = (const float*)d_in[3];
    const float* bihL = (const float*)d_in[4];
    const float* bhhL = (const float*)d_in[5];
    const float* xA   = (const float*)d_in[6];
    const void*  mA   = d_in[7];
    const float* WihA = (const float*)d_in[8];
    const float* WhhA = (const float*)d_in[9];
    const float* bihA = (const float*)d_in[10];
    const float* bhhA = (const float*)d_in[11];
    const float* xI   = (const float*)d_in[12];
    const void*  mI   = d_in[13];
    const float* WihI = (const float*)d_in[14];
    const float* WhhI = (const float*)d_in[15];
    const float* bihI = (const float*)d_in[16];
    const float* bhhI = (const float*)d_in[17];
    const int*   seqlen = (const int*)d_in[18];
    const float* lmask  = (const float*)d_in[19];
    const float* W1 = (const float*)d_in[20];
    const float* b1 = (const float*)d_in[21];
    const float* W2 = (const float*)d_in[22];
    const float* b2 = (const float*)d_in[23];
    float* out = (float*)d_out;

    // Byte-accurate workspace layout, 64B aligned blocks.
    char* base = (char*)d_ws;
    size_t off = 0;
    auto take = [&](size_t bytes) -> char* {
        char* p = base + off;
        off += (bytes + 63) & ~(size_t)63;
        return p;
    };
    unsigned int* cnt = (unsigned int*)take(256 * 64 * sizeof(unsigned int)); // per-chunk slices
    int*   modep = (int*)take(64);
    float* wbuf  = (float*)take(512 * sizeof(float));
    float* hcL   = (float*)take((size_t)N_ * 2 * HL * sizeof(float));
    float* hcA   = (float*)take((size_t)N_ * 2 * HA * sizeof(float));
    float* hcI   = (float*)take((size_t)N_ * 2 * HI * sizeof(float));
    float* zbuf  = (float*)take((size_t)N_ * 8 * 304 * sizeof(float));
    bf16*  hsL   = (bf16*)take((size_t)N_ * T_ * HL * sizeof(bf16));
    bf16*  hsA   = (bf16*)take((size_t)N_ * T_ * HA * sizeof(bf16));
    bf16*  hsI   = (bf16*)take((size_t)N_ * T_ * HI * sizeof(bf16));

    // largest t-chunk whose xz buffers fit in the remaining workspace
    const size_t xz_per_tc = (size_t)N_ * K_ * (H4L + H4A + H4I) * sizeof(float);
    int Tc = T_;
    while (Tc > 1 && off + (size_t)Tc * xz_per_tc + 256 > ws_size) Tc >>= 1;
    if (off + (size_t)Tc * xz_per_tc + 256 > ws_size) {
        hipMemsetAsync(d_out, 0, (size_t)out_size * sizeof(float), stream);
        return;
    }
    float* xzL = (float*)take((size_t)N_ * Tc * K_ * H4L * sizeof(float));
    float* xzA = (float*)take((size_t)N_ * Tc * K_ * H4A * sizeof(float));
    float* xzI = (float*)take((size_t)N_ * Tc * K_ * H4I * sizeof(float));

    const int nchunks = T_ / Tc;
    hipMemsetAsync(cnt, 0, (size_t)nchunks * 64 * sizeof(unsigned int), stream);
    mask_mode_detect<<<1, 256, 0, stream>>>((const unsigned int*)mL, modep);
    wprep<<<1, 512, 0, stream>>>(W1, b1, W2, b2, wbuf);

    const int My = (N_ * Tc * K_) / 64;
    for (int c = 0; c < nchunks; ++c) {
        const int t0 = c * Tc;
        gemm_xz<<<dim3((H4L + 63) / 64, My), 256, 0, stream>>>(
            xL, WihL, bihL, bhhL, seqlen, xzL, DL, H4L, Tc, t0);
        gemm_xz<<<dim3((H4A + 63) / 64, My), 256, 0, stream>>>(
            xA, WihA, bihA, bhhA, seqlen, xzA, DA, H4A, Tc, t0);
        gemm_xz<<<dim3((H4I + 63) / 64, My), 256, 0, stream>>>(
            xI, WihI, bihI, bhhI, seqlen, xzI, DI, H4I, Tc, t0);
        recur_small<<<2 * N_, 512, 0, stream>>>(
            WhhA, WhhI, mA, mI, modep, seqlen, xzA, xzI, hsA, hsI, hcA, hcI, Tc, t0);
        recur_ling<<<4 * N_, 512, 0, stream>>>(
            WhhL, mL, modep, seqlen, xzL, hsL, hcL, zbuf, cnt + (size_t)c * 64, Tc, t0);
    }
    out_kernel<<<N_, T_, 0, stream>>>(wbuf, (const ushort*)hsL, (const ushort*)hsA,
                                      (const ushort*)hsI, lmask, out);
}

// Round 7
// 4291.500 us; speedup vs baseline: 1.5026x; 1.4290x over previous
//
#include <hip/hip_runtime.h>
#include <hip/hip_bf16.h>
#include <stdint.h>

// Problem dims
#define N_ 64
#define T_ 256
#define K_ 4

#define DL 300
#define HL 300
#define H4L 1200

#define DA 88
#define HA 64
#define H4A 256

#define DI 128
#define HI 128
#define H4I 512

typedef __hip_bfloat16 bf16;
typedef __attribute__((ext_vector_type(8))) short bf16x8;
typedef __attribute__((ext_vector_type(4))) float f32x4;

__device__ __forceinline__ float sigf(float x) { return 1.0f / (1.0f + expf(-x)); }

// Mask dtype detected at runtime: 0 = int32, 1 = uint8, 2 = float32.
__device__ __forceinline__ int read_mask(const void* m, size_t idx, int mode) {
    if (mode == 0) return ((const int*)m)[idx];
    if (mode == 1) return (int)((const unsigned char*)m)[idx];
    return ((const float*)m)[idx] != 0.0f;
}

__global__ void mask_mode_detect(const unsigned int* __restrict__ m, int* __restrict__ modep) {
    __shared__ unsigned int f[2];
    if (threadIdx.x == 0) { f[0] = 0u; f[1] = 0u; }
    __syncthreads();
    unsigned int gt1 = 0, f32one = 0;
    for (int i = threadIdx.x; i < 4096; i += 256) {
        const unsigned int v = m[i];
        if (v > 1u) gt1 = 1u;
        if (v == 0x3F800000u) f32one = 1u;
    }
    if (gt1) atomicOr(&f[0], 1u);
    if (f32one) atomicOr(&f[1], 1u);
    __syncthreads();
    if (threadIdx.x == 0) modep[0] = f[0] ? (f[1] ? 2 : 1) : 0;
}

// ---------------------------------------------------------------------------
// xproj GEMM via MFMA bf16: XZ[r][j] = bf16( sum_d X[r][d]*W[j][d] + bias[j] ).
// 64x64 tile, 256 thr = 4 waves; wave w owns rows [16w,16w+16) x 64 cols:
// 4 x mfma_f32_16x16x32_bf16 per K-step (K=32). f32->bf16 conversion happens
// during LDS staging (stride 40 shorts = 80B: bank-friendly, 16B-aligned).
// Fragment maps (guide-verified): A/B lane layout idx%16 + k=(lane/16)*8+i;
// C/D col=lane&15, row=(lane>>4)*4+reg.
// ---------------------------------------------------------------------------
__global__ __launch_bounds__(256) void gemm_xz_mfma(
    const float* __restrict__ X, const float* __restrict__ W,
    const float* __restrict__ bih, const float* __restrict__ bhh,
    const int* __restrict__ seqlen,
    bf16* __restrict__ XZ,
    int D, int H4, int Tc, int t0)
{
    __shared__ __align__(16) unsigned short Xs[64 * 40];
    __shared__ __align__(16) unsigned short Ws[64 * 40];
    const int tid = threadIdx.x;
    const int m0 = blockIdx.y * 64;
    const int j0 = blockIdx.x * 64;
    const int Tc4 = Tc * 4;

    int act = 0;
    if (tid < 64) {
        const int rr = m0 + tid;
        const int n = rr / Tc4;
        const int ttt = (rr % Tc4) >> 2;
        act = (t0 + ttt) < seqlen[n];
    }
    if (!__syncthreads_or(act)) return;

    // staging role: thread stages X row (tid>>2) and W col (tid>>2), d-quarter tid&3
    const int srow = tid >> 2;
    const int sq = tid & 3;
    const int rr = m0 + srow;
    const int n = rr / Tc4;
    const int ttt = (rr % Tc4) >> 2;
    const int kk_ = rr & 3;
    const float* xrow = X + ((size_t)((n * T_ + t0 + ttt) * 4 + kk_)) * D;
    const int wcol = j0 + srow;
    const bool wvalid = wcol < H4;
    const float* wrow = W + (size_t)(wvalid ? wcol : 0) * D;

    const int lane = tid & 63;
    const int wv = tid >> 6;         // wave 0..3
    const int fr = lane & 15;        // frag row/col
    const int fk = (lane >> 4) * 8;  // frag k-offset

    f32x4 acc[4] = {{0,0,0,0},{0,0,0,0},{0,0,0,0},{0,0,0,0}};

    const int nks = (D + 31) >> 5;
    for (int ks = 0; ks < nks; ++ks) {
        const int d0 = ks * 32 + sq * 8;
        float xf[8], wf[8];
        if (d0 + 7 < D) {
            const float4 a0 = *(const float4*)(xrow + d0);
            const float4 a1 = *(const float4*)(xrow + d0 + 4);
            xf[0]=a0.x; xf[1]=a0.y; xf[2]=a0.z; xf[3]=a0.w;
            xf[4]=a1.x; xf[5]=a1.y; xf[6]=a1.z; xf[7]=a1.w;
            const float4 b0 = *(const float4*)(wrow + d0);
            const float4 b1 = *(const float4*)(wrow + d0 + 4);
            wf[0]=b0.x; wf[1]=b0.y; wf[2]=b0.z; wf[3]=b0.w;
            wf[4]=b1.x; wf[5]=b1.y; wf[6]=b1.z; wf[7]=b1.w;
#pragma unroll
            for (int e = 0; e < 8; ++e) if (!wvalid) wf[e] = 0.0f;
        } else {
#pragma unroll
            for (int e = 0; e < 8; ++e) {
                const int d = d0 + e;
                xf[e] = (d < D) ? xrow[d] : 0.0f;
                wf[e] = (d < D && wvalid) ? wrow[d] : 0.0f;
            }
        }
        union { unsigned short u[8]; uint4 v; } px, pw;
#pragma unroll
        for (int e = 0; e < 8; ++e) {
            bf16 hx = __float2bfloat16(xf[e]);
            bf16 hw = __float2bfloat16(wf[e]);
            px.u[e] = *(unsigned short*)&hx;
            pw.u[e] = *(unsigned short*)&hw;
        }
        __syncthreads();   // prev iter's frag reads complete before overwrite
        *(uint4*)&Xs[srow * 40 + sq * 8] = px.v;
        *(uint4*)&Ws[srow * 40 + sq * 8] = pw.v;
        __syncthreads();
        const bf16x8 a = *(const bf16x8*)&Xs[(wv * 16 + fr) * 40 + fk];
#pragma unroll
        for (int c = 0; c < 4; ++c) {
            const bf16x8 b = *(const bf16x8*)&Ws[(c * 16 + fr) * 40 + fk];
            acc[c] = __builtin_amdgcn_mfma_f32_16x16x32_bf16(a, b, acc[c], 0, 0, 0);
        }
    }
    // epilogue: add bias, convert, store bf16
#pragma unroll
    for (int c = 0; c < 4; ++c) {
        const int col = j0 + c * 16 + fr;
        if (col < H4) {
            const float bias = bih[col] + bhh[col];
#pragma unroll
            for (int rg = 0; rg < 4; ++rg) {
                const int row = m0 + wv * 16 + (lane >> 4) * 4 + rg;
                XZ[(size_t)row * H4 + col] = __float2bfloat16(acc[c][rg] + bias);
            }
        }
    }
}

// ---------------------------------------------------------------------------
// Image + acoustic recurrences. 128 blocks x 512 threads, (512,1) so the
// weight arrays (128 / 64 VGPRs) fit under a 256-VGPR cap ((512,2) capped at
// 128 and spilled — round-5 lesson). xz now bf16.
// ---------------------------------------------------------------------------
__global__ __launch_bounds__(512, 1) void recur_small(
    const float* __restrict__ WhhA, const float* __restrict__ WhhI,
    const void* __restrict__ mA, const void* __restrict__ mI,
    const int* __restrict__ modep,
    const int* __restrict__ seqlen,
    const bf16* __restrict__ xzA, const bf16* __restrict__ xzI,
    bf16* __restrict__ hsA, bf16* __restrict__ hsI,
    float* __restrict__ hcA, float* __restrict__ hcI,
    int Tc, int t0)
{
    __shared__ __align__(16) float h_s[128];
    __shared__ __align__(16) float c_s[128];
    __shared__ __align__(16) float z_s[512];
    const int tid = threadIdx.x;
    const int mode = modep[0];

    if (blockIdx.x < N_) {
        // ---------------- image ----------------
        const int n = blockIdx.x;
        const int seqn = seqlen[n];
        float w[128];
        {
            const float4* wp = (const float4*)(WhhI + (size_t)tid * 128);
#pragma unroll
            for (int jj = 0; jj < 32; ++jj) {
                const float4 v = wp[jj];
                w[4 * jj] = v.x; w[4 * jj + 1] = v.y; w[4 * jj + 2] = v.z; w[4 * jj + 3] = v.w;
            }
        }
        if (tid < 128) {
            if (t0 == 0) { h_s[tid] = 0.0f; c_s[tid] = 0.0f; }
            else { h_s[tid] = hcI[n * 256 + tid]; c_s[tid] = hcI[n * 256 + 128 + tid]; }
        }
        __syncthreads();
#pragma unroll 1
        for (int tt = 0; tt < Tc; ++tt) {
            const int t = t0 + tt;
            if (t >= seqn) {
                if (tid < 128) hsI[((size_t)(n * T_ + t)) * 128 + tid] = __float2bfloat16(0.0f);
                continue;
            }
            const size_t xbase = ((size_t)((n * Tc + tt) * 4)) * 512;
            const size_t mbase = (size_t)(n * T_ + t) * 4;
#pragma unroll 1
            for (int k = 0; k < 4; ++k) {
                if (!read_mask(mI, mbase + k, mode)) continue;
                float acc = __bfloat162float(xzI[xbase + k * 512 + tid]);
                const float4* hp = (const float4*)h_s;
#pragma unroll
                for (int jj = 0; jj < 32; ++jj) {
                    const float4 hv = hp[jj];
                    acc += w[4 * jj] * hv.x + w[4 * jj + 1] * hv.y
                         + w[4 * jj + 2] * hv.z + w[4 * jj + 3] * hv.w;
                }
                z_s[tid] = acc;
                __syncthreads();
                if (tid < 128) {
                    const float zi = z_s[tid], zf = z_s[128 + tid];
                    const float zg = z_s[256 + tid], zo = z_s[384 + tid];
                    const float cc = sigf(zf) * c_s[tid] + sigf(zi) * tanhf(zg);
                    c_s[tid] = cc;
                    h_s[tid] = sigf(zo) * tanhf(cc);
                }
                __syncthreads();
            }
            if (tid < 128) hsI[((size_t)(n * T_ + t)) * 128 + tid] = __float2bfloat16(h_s[tid]);
        }
        if (tid < 128) { hcI[n * 256 + tid] = h_s[tid]; hcI[n * 256 + 128 + tid] = c_s[tid]; }
    } else {
        // ---------------- acoustic ----------------
        const int n = blockIdx.x - N_;
        const int seqn = seqlen[n];
        float w[64];
        if (tid < 256) {
            const float4* wp = (const float4*)(WhhA + (size_t)tid * 64);
#pragma unroll
            for (int jj = 0; jj < 16; ++jj) {
                const float4 v = wp[jj];
                w[4 * jj] = v.x; w[4 * jj + 1] = v.y; w[4 * jj + 2] = v.z; w[4 * jj + 3] = v.w;
            }
        }
        if (tid < 64) {
            if (t0 == 0) { h_s[tid] = 0.0f; c_s[tid] = 0.0f; }
            else { h_s[tid] = hcA[n * 128 + tid]; c_s[tid] = hcA[n * 128 + 64 + tid]; }
        }
        __syncthreads();
#pragma unroll 1
        for (int tt = 0; tt < Tc; ++tt) {
            const int t = t0 + tt;
            if (t >= seqn) {
                if (tid < 64) hsA[((size_t)(n * T_ + t)) * 64 + tid] = __float2bfloat16(0.0f);
                continue;
            }
            const size_t xbase = ((size_t)((n * Tc + tt) * 4)) * 256;
            const size_t mbase = (size_t)(n * T_ + t) * 4;
#pragma unroll 1
            for (int k = 0; k < 4; ++k) {
                if (!read_mask(mA, mbase + k, mode)) continue;
                if (tid < 256) {
                    float acc = __bfloat162float(xzA[xbase + k * 256 + tid]);
                    const float4* hp = (const float4*)h_s;
#pragma unroll
                    for (int jj = 0; jj < 16; ++jj) {
                        const float4 hv = hp[jj];
                        acc += w[4 * jj] * hv.x + w[4 * jj + 1] * hv.y
                             + w[4 * jj + 2] * hv.z + w[4 * jj + 3] * hv.w;
                    }
                    z_s[tid] = acc;
                }
                __syncthreads();
                if (tid < 64) {
                    const float zi = z_s[tid], zf = z_s[64 + tid];
                    const float zg = z_s[128 + tid], zo = z_s[192 + tid];
                    const float cc = sigf(zf) * c_s[tid] + sigf(zi) * tanhf(zg);
                    c_s[tid] = cc;
                    h_s[tid] = sigf(zo) * tanhf(cc);
                }
                __syncthreads();
            }
            if (tid < 64) hsA[((size_t)(n * T_ + t)) * 64 + tid] = __float2bfloat16(h_s[tid]);
        }
        if (tid < 64) { hcA[n * 128 + tid] = h_s[tid]; hcA[n * 128 + 64 + tid] = c_s[tid]; }
    }
}

// ---------------------------------------------------------------------------
// Linguistic recurrence: 4 blocks per sample (one per gate), 512 threads.
// (512,1): 256-VGPR cap under either launch_bounds interpretation — round 5's
// (512,2) was treated as 2 blocks/CU -> 128-VGPR cap -> weights spilled
// (observed VGPR_Count=128). 8 col-chunks x 38 cols x 5 row-stripes = 190
// weight VGPRs/thread, fits.
// ---------------------------------------------------------------------------
__global__ __launch_bounds__(512, 1) void recur_ling(
    const float* __restrict__ Whh,
    const void* __restrict__ mask,
    const int* __restrict__ modep,
    const int* __restrict__ seqlen,
    const bf16* __restrict__ xz,
    bf16* __restrict__ hs,
    float* __restrict__ hc,
    float* __restrict__ zbuf,       // [N][4][2][304]
    unsigned int* __restrict__ cnt, // [N] slice for THIS chunk, pre-zeroed
    int Tc, int t0)
{
    __shared__ float h_s[304];      // padded; [300..303] stay 0
    __shared__ float c_s[304];
    __shared__ float zp_s[8 * 308];
    const int tid = threadIdx.x;
    // XCD-co-locating swizzle: all 4 gate blocks of a sample on one XCD.
    const int xcd = blockIdx.x & 7;
    const int idx = blockIdx.x >> 3;
    const int n = xcd * 8 + (idx >> 2);
    const int g = idx & 3;
    const int seqn = seqlen[n];
    const int mode = modep[0];

    // chunk = tid&7 owns cols [chunk*38, +38); rows r = (tid>>3) + 64*s.
    const int chunk = tid & 7;
    const int rb = tid >> 3;        // 0..63
    const int cj = chunk * 38;
    float w[5][38];
#pragma unroll
    for (int s = 0; s < 5; ++s) {
        const int r = rb + 64 * s;
        const bool rv = (r < 300);
        const float* wp = Whh + ((size_t)(g * 300 + (rv ? r : 0))) * 300;
#pragma unroll
        for (int j = 0; j < 38; ++j) {
            const int col = cj + j;
            w[s][j] = (rv && col < 300) ? wp[col] : 0.0f;
        }
    }
    for (int r = tid; r < 304; r += 512) {
        if (t0 == 0 || r >= 300) { h_s[r] = 0.0f; c_s[r] = 0.0f; }
        else { h_s[r] = hc[n * 600 + r]; c_s[r] = hc[n * 600 + 300 + r]; }
    }
    __syncthreads();

    unsigned int serial = 0;  // completed exchange rounds (same across 4 blocks)
    unsigned int* const cntn = &cnt[n];
    float* const pub = zbuf + ((size_t)(n * 4 + g)) * 2 * 304;
    float* const zb  = zbuf + (size_t)n * 8 * 304;   // slot (g,par) at (g*2+par)*304

#pragma unroll 1
    for (int tt = 0; tt < Tc; ++tt) {
        const int t = t0 + tt;
        if (t >= seqn) {
            if (g == 0 && tid < 300)
                hs[((size_t)(n * T_ + t)) * 300 + tid] = __float2bfloat16(0.0f);
            continue;
        }
        const size_t mbase = (size_t)(n * T_ + t) * 4;
        const bf16* xzt = xz + ((size_t)((n * Tc + tt) * 4)) * 1200;
#pragma unroll 1
        for (int k = 0; k < 4; ++k) {
            if (!read_mask(mask, mbase + k, mode)) continue;
            const int par = (int)(serial & 1u);
            float a0 = 0.f, a1 = 0.f, a2 = 0.f, a3 = 0.f, a4 = 0.f;
#pragma unroll
            for (int j = 0; j < 38; ++j) {
                const float hv = h_s[cj + j];   // 8 addrs/wave, 8-way broadcast
                a0 += w[0][j] * hv;
                a1 += w[1][j] * hv;
                a2 += w[2][j] * hv;
                a3 += w[3][j] * hv;
                a4 += w[4][j] * hv;
            }
            zp_s[chunk * 308 + rb]       = a0;
            zp_s[chunk * 308 + rb + 64]  = a1;
            zp_s[chunk * 308 + rb + 128] = a2;
            zp_s[chunk * 308 + rb + 192] = a3;
            if (rb < 44) zp_s[chunk * 308 + rb + 256] = a4;
            __syncthreads();
            // reduce 8 col-chunks + xz slice; publish this gate's z (parity slot)
            if (tid < 300) {
                const bf16* xg = xzt + k * 1200 + g * 300;
                float z = __bfloat162float(xg[tid]);
#pragma unroll
                for (int c = 0; c < 8; ++c) z += zp_s[c * 308 + tid];
                __hip_atomic_store(&pub[par * 304 + tid], z, __ATOMIC_RELAXED, __HIP_MEMORY_SCOPE_AGENT);
            }
            __syncthreads();
            if (tid == 0) {
                __hip_atomic_fetch_add(cntn, 1u, __ATOMIC_RELEASE, __HIP_MEMORY_SCOPE_AGENT);
                const unsigned int target = 4u * (serial + 1u);
                unsigned int v = __hip_atomic_load(cntn, __ATOMIC_ACQUIRE, __HIP_MEMORY_SCOPE_AGENT);
                long guard = 0;
                while (v < target && guard < (1L << 24)) {
                    __builtin_amdgcn_s_sleep(1);
                    v = __hip_atomic_load(cntn, __ATOMIC_ACQUIRE, __HIP_MEMORY_SCOPE_AGENT);
                    ++guard;
                }
            }
            __syncthreads();
            // all 4 gates' parity slots visible; redundantly update h,c
            if (tid < 300) {
                const float zi = __hip_atomic_load(&zb[(0 + par) * 304 + tid], __ATOMIC_RELAXED, __HIP_MEMORY_SCOPE_AGENT);
                const float zf = __hip_atomic_load(&zb[(2 + par) * 304 + tid], __ATOMIC_RELAXED, __HIP_MEMORY_SCOPE_AGENT);
                const float zg = __hip_atomic_load(&zb[(4 + par) * 304 + tid], __ATOMIC_RELAXED, __HIP_MEMORY_SCOPE_AGENT);
                const float zo = __hip_atomic_load(&zb[(6 + par) * 304 + tid], __ATOMIC_RELAXED, __HIP_MEMORY_SCOPE_AGENT);
                const float cc = sigf(zf) * c_s[tid] + sigf(zi) * tanhf(zg);
                c_s[tid] = cc;
                h_s[tid] = sigf(zo) * tanhf(cc);
            }
            __syncthreads();
            ++serial;
        }
        if (g == 0 && tid < 300)
            hs[((size_t)(n * T_ + t)) * 300 + tid] = __float2bfloat16(h_s[tid]);
    }
    if (g == 0 && tid < 300) {
        hc[n * 600 + tid] = h_s[tid];
        hc[n * 600 + 300 + tid] = c_s[tid];
    }
}

// ---------------------------------------------------------------------------
// Fusion head collapse: w = W2@W1 (492 weights), c0 = W2.b1 + b2 (wbuf[500]).
// ---------------------------------------------------------------------------
__global__ void wprep(const float* __restrict__ W1, const float* __restrict__ b1,
                      const float* __restrict__ W2, const float* __restrict__ b2,
                      float* __restrict__ wbuf)
{
    const int j = threadIdx.x;
    if (j < 492) {
        float a = 0.0f;
        for (int r = 0; r < 256; ++r) a += W2[r] * W1[r * 492 + j];
        wbuf[j] = a;
    } else if (j == 492) {
        float a = 0.0f;
        for (int r = 0; r < 256; ++r) a += W2[r] * b1[r];
        wbuf[500] = a + b2[0];
    }
}

// ---------------------------------------------------------------------------
// Output. The reference does hs.reshape(n,t,h) on (T,N,h)-ordered scan output
// WITHOUT transposing — fused[i,j] = hs_scan[i*4 + j//64, j%64]. We store hs
// as [n][t][h], so gather from (n_src = j&63, t_src = i*4 + (j>>6)).
// ---------------------------------------------------------------------------
__device__ __forceinline__ float bflo(unsigned int u) { return __uint_as_float(u << 16); }
__device__ __forceinline__ float bfhi(unsigned int u) { return __uint_as_float(u & 0xFFFF0000u); }

__global__ void out_kernel(const float* __restrict__ wbuf,
                           const ushort* __restrict__ hsL, const ushort* __restrict__ hsA,
                           const ushort* __restrict__ hsI,
                           const float* __restrict__ lmask, float* __restrict__ out)
{
    const int i = blockIdx.x;    // output n
    const int j = threadIdx.x;   // output t
    const int nn = j & 63;             // source sample
    const int tt = i * 4 + (j >> 6);   // source time
    const size_t src = (size_t)nn * T_ + tt;
    float acc = wbuf[500];
    const uint2* hl = (const uint2*)(hsL + src * HL);
#pragma unroll
    for (int u = 0; u < HL / 4; ++u) {
        const uint2 v = hl[u];
        const float4 w4 = *(const float4*)&wbuf[4 * u];
        acc += bflo(v.x) * w4.x + bfhi(v.x) * w4.y + bflo(v.y) * w4.z + bfhi(v.y) * w4.w;
    }
    const uint2* ha = (const uint2*)(hsA + src * HA);
#pragma unroll
    for (int u = 0; u < HA / 4; ++u) {
        const uint2 v = ha[u];
        const float4 w4 = *(const float4*)&wbuf[300 + 4 * u];
        acc += bflo(v.x) * w4.x + bfhi(v.x) * w4.y + bflo(v.y) * w4.z + bfhi(v.y) * w4.w;
    }
    const uint2* hi = (const uint2*)(hsI + src * HI);
#pragma unroll
    for (int u = 0; u < HI / 4; ++u) {
        const uint2 v = hi[u];
        const float4 w4 = *(const float4*)&wbuf[364 + 4 * u];
        acc += bflo(v.x) * w4.x + bfhi(v.x) * w4.y + bflo(v.y) * w4.z + bfhi(v.y) * w4.w;
    }
    const size_t nt = (size_t)i * T_ + j;
    out[nt] = acc * lmask[nt];
}

// ---------------------------------------------------------------------------
extern "C" void kernel_launch(void* const* d_in, const int* in_sizes, int n_in,
                              void* d_out, int out_size, void* d_ws, size_t ws_size,
                              hipStream_t stream)
{
    (void)in_sizes; (void)n_in;
    const float* xL   = (const float*)d_in[0];
    const void*  mL   = d_in[1];
    const float* WihL = (const float*)d_in[2];
    const float* WhhL = (const float*)d_in[3];
    const float* bihL = (const float*)d_in[4];
    const float* bhhL = (const float*)d_in[5];
    const float* xA   = (const float*)d_in[6];
    const void*  mA   = d_in[7];
    const float* WihA = (const float*)d_in[8];
    const float* WhhA = (const float*)d_in[9];
    const float* bihA = (const float*)d_in[10];
    const float* bhhA = (const float*)d_in[11];
    const float* xI   = (const float*)d_in[12];
    const void*  mI   = d_in[13];
    const float* WihI = (const float*)d_in[14];
    const float* WhhI = (const float*)d_in[15];
    const float* bihI = (const float*)d_in[16];
    const float* bhhI = (const float*)d_in[17];
    const int*   seqlen = (const int*)d_in[18];
    const float* lmask  = (const float*)d_in[19];
    const float* W1 = (const float*)d_in[20];
    const float* b1 = (const float*)d_in[21];
    const float* W2 = (const float*)d_in[22];
    const float* b2 = (const float*)d_in[23];
    float* out = (float*)d_out;

    // Byte-accurate workspace layout, 64B aligned blocks.
    char* base = (char*)d_ws;
    size_t off = 0;
    auto take = [&](size_t bytes) -> char* {
        char* p = base + off;
        off += (bytes + 63) & ~(size_t)63;
        return p;
    };
    unsigned int* cnt = (unsigned int*)take(256 * 64 * sizeof(unsigned int)); // per-chunk slices
    int*   modep = (int*)take(64);
    float* wbuf  = (float*)take(512 * sizeof(float));
    float* hcL   = (float*)take((size_t)N_ * 2 * HL * sizeof(float));
    float* hcA   = (float*)take((size_t)N_ * 2 * HA * sizeof(float));
    float* hcI   = (float*)take((size_t)N_ * 2 * HI * sizeof(float));
    float* zbuf  = (float*)take((size_t)N_ * 8 * 304 * sizeof(float));
    bf16*  hsL   = (bf16*)take((size_t)N_ * T_ * HL * sizeof(bf16));
    bf16*  hsA   = (bf16*)take((size_t)N_ * T_ * HA * sizeof(bf16));
    bf16*  hsI   = (bf16*)take((size_t)N_ * T_ * HI * sizeof(bf16));

    // largest t-chunk whose bf16 xz buffers fit in the remaining workspace
    const size_t xz_per_tc = (size_t)N_ * K_ * (H4L + H4A + H4I) * sizeof(bf16);
    int Tc = T_;
    while (Tc > 1 && off + (size_t)Tc * xz_per_tc + 256 > ws_size) Tc >>= 1;
    if (off + (size_t)Tc * xz_per_tc + 256 > ws_size) {
        hipMemsetAsync(d_out, 0, (size_t)out_size * sizeof(float), stream);
        return;
    }
    bf16* xzL = (bf16*)take((size_t)N_ * Tc * K_ * H4L * sizeof(bf16));
    bf16* xzA = (bf16*)take((size_t)N_ * Tc * K_ * H4A * sizeof(bf16));
    bf16* xzI = (bf16*)take((size_t)N_ * Tc * K_ * H4I * sizeof(bf16));

    const int nchunks = T_ / Tc;
    hipMemsetAsync(cnt, 0, (size_t)nchunks * 64 * sizeof(unsigned int), stream);
    mask_mode_detect<<<1, 256, 0, stream>>>((const unsigned int*)mL, modep);
    wprep<<<1, 512, 0, stream>>>(W1, b1, W2, b2, wbuf);

    const int My = (N_ * Tc * K_) / 64;
    for (int c = 0; c < nchunks; ++c) {
        const int t0 = c * Tc;
        gemm_xz_mfma<<<dim3((H4L + 63) / 64, My), 256, 0, stream>>>(
            xL, WihL, bihL, bhhL, seqlen, xzL, DL, H4L, Tc, t0);
        gemm_xz_mfma<<<dim3((H4A + 63) / 64, My), 256, 0, stream>>>(
            xA, WihA, bihA, bhhA, seqlen, xzA, DA, H4A, Tc, t0);
        gemm_xz_mfma<<<dim3((H4I + 63) / 64, My), 256, 0, stream>>>(
            xI, WihI, bihI, bhhI, seqlen, xzI, DI, H4I, Tc, t0);
        recur_small<<<2 * N_, 512, 0, stream>>>(
            WhhA, WhhI, mA, mI, modep, seqlen, xzA, xzI, hsA, hsI, hcA, hcI, Tc, t0);
        recur_ling<<<4 * N_, 512, 0, stream>>>(
            WhhL, mL, modep, seqlen, xzL, hsL, hcL, zbuf, cnt + (size_t)c * 64, Tc, t0);
    }
    out_kernel<<<N_, T_, 0, stream>>>(wbuf, (const ushort*)hsL, (const ushort*)hsA,
                                      (const ushort*)hsI, lmask, out);
}